// Round 8
// baseline (291.651 us; speedup 1.0000x reference)
//
#include <hip/hip_runtime.h>
#include <hip/hip_bf16.h>
#include <math.h>

#define F_IN 512
#define HOUT 64      // HEADS*C1
#define HEADS 8
#define C1 8
#define NCLS 40
#define NEG 0.2f

#define DPB 256            // dsts per bucket
#define CAP 8064           // staging capacity per bucket
#define EPT 32             // edges per thread in passA
#define WLD 520            // padded K-stride of transposed bf16 weights

typedef __attribute__((ext_vector_type(8))) short short8;
typedef __attribute__((ext_vector_type(4))) float f32x4;

__device__ __forceinline__ ushort f2b(float f) {
    union { float f; unsigned u; } v; v.f = f;
    unsigned r = (v.u + 0x7FFFu + ((v.u >> 16) & 1u)) >> 16;   // RNE
    return (ushort)r;
}
__device__ __forceinline__ float b2f(ushort b) {
    union { unsigned u; float f; } v; v.u = ((unsigned)b) << 16;
    return v.f;
}
__device__ __forceinline__ float b2f_lo(unsigned u) { union { unsigned u; float f; } v; v.u = u << 16; return v.f; }
__device__ __forceinline__ float b2f_hi(unsigned u) { union { unsigned u; float f; } v; v.u = u & 0xFFFF0000u; return v.f; }

// ---------------- CSR build: bucketed counting sort (packed 4B staging) ----------------

__global__ __launch_bounds__(512) void init_k(int* __restrict__ gcur, int nbuck) {
    int b = blockIdx.x * 512 + threadIdx.x;
    if (b < nbuck) gcur[b] = b * CAP;
}

__global__ __launch_bounds__(256) void passA_k(const int* __restrict__ ei, int* __restrict__ gcur,
                                               int* __restrict__ bkt, int E, int Etot, int nbuck) {
    __shared__ int hist[512];
    __shared__ int lbase[512];
    int t = threadIdx.x;
    int base_e = blockIdx.x * (256 * EPT);
    for (int j = t; j < nbuck; j += 256) hist[j] = 0;
    __syncthreads();
    for (int j = 0; j < EPT; ++j) {
        int idx = base_e + j * 256 + t;
        if (idx < Etot) {
            int d = (idx < E) ? ei[E + idx] : (idx - E);
            atomicAdd(&hist[d >> 8], 1);
        }
    }
    __syncthreads();
    for (int j = t; j < nbuck; j += 256) {
        int c = hist[j];
        lbase[j] = c ? atomicAdd(&gcur[j], c) : 0;
    }
    __syncthreads();
    for (int j = t; j < nbuck; j += 256) hist[j] = 0;
    __syncthreads();
    for (int j = 0; j < EPT; ++j) {
        int idx = base_e + j * 256 + t;
        if (idx < Etot) {
            int s, d;
            if (idx < E) { s = ei[idx]; d = ei[E + idx]; } else { s = idx - E; d = idx - E; }
            int b = d >> 8;
            int slot = atomicAdd(&hist[b], 1);
            bkt[lbase[b] + slot] = (s << 8) | (d & 255);
        }
    }
}

__global__ __launch_bounds__(512) void bscan_k(const int* __restrict__ gcur, int* __restrict__ bbase,
                                               int* __restrict__ rowptr, int nbuck, int n, int Etot) {
    __shared__ int wsum[8];
    int t = threadIdx.x;
    int v = (t < nbuck) ? gcur[t] - t * CAP : 0;
    int lane = t & 63, w = t >> 6;
    int ss = v;
#pragma unroll
    for (int off = 1; off < 64; off <<= 1) { int t2 = __shfl_up(ss, off); if (lane >= off) ss += t2; }
    if (lane == 63) wsum[w] = ss;
    __syncthreads();
    int woff = 0;
    for (int j = 0; j < w; ++j) woff += wsum[j];
    if (t < nbuck) bbase[t] = woff + ss - v;
    if (t == 0) rowptr[n] = Etot;
}

__global__ __launch_bounds__(256) void passB_k(const int* __restrict__ bkt, const int* __restrict__ gcur,
                                               const int* __restrict__ bbase, int* __restrict__ rowptr,
                                               int* __restrict__ col, int n) {
    __shared__ int hist[DPB];
    __shared__ int lcur[DPB];
    __shared__ int wsum[4];
    int b = blockIdx.x;
    int t = threadIdx.x;
    int cnt = gcur[b] - b * CAP;
    int base = bbase[b];
    int d0 = b * DPB;
    int ndst = min(DPB, n - d0);
    const int* src = bkt + (size_t)b * CAP;
    hist[t] = 0;
    __syncthreads();
    for (int e = t; e < cnt; e += 256) {
        atomicAdd(&hist[src[e] & 255], 1);
    }
    __syncthreads();
    int v = hist[t];
    int lane = t & 63, w = t >> 6;
    int ss = v;
#pragma unroll
    for (int off = 1; off < 64; off <<= 1) { int t2 = __shfl_up(ss, off); if (lane >= off) ss += t2; }
    if (lane == 63) wsum[w] = ss;
    __syncthreads();
    int woff = 0;
    for (int j = 0; j < w; ++j) woff += wsum[j];
    int excl = woff + ss - v;
    if (t < ndst) rowptr[d0 + t] = base + excl;
    lcur[t] = excl;
    __syncthreads();
    for (int e = t; e < cnt; e += 256) {
        int u = src[e];
        int pos = atomicAdd(&lcur[u & 255], 1);
        col[base + pos] = (int)((unsigned)u >> 8);
    }
}

// ---------------- weight prep ----------------

__global__ __launch_bounds__(256) void wconv_k(const float* __restrict__ W, ushort* __restrict__ Wtg) {
    int idx = blockIdx.x * 256 + threadIdx.x;
    if (idx >= F_IN * HOUT) return;
    int k = idx >> 6, c = idx & 63;
    Wtg[(size_t)c * WLD + k] = f2b(W[idx]);
}

// W1a[k][c] = sum_j W1[k][8*(c&7)+j] * (c<8 ? asw1 : adw1)[(c&7)*8+j]; stored transposed [16][WLD]
__global__ __launch_bounds__(256) void wprep_k(const float* __restrict__ W1, const float* __restrict__ asw,
                                               const float* __restrict__ adw, ushort* __restrict__ W1at) {
    int idx = blockIdx.x * 256 + threadIdx.x;
    if (idx >= 16 * F_IN) return;
    int k = idx & 511, c = idx >> 9;
    int h = c & 7;
    const float* wv = (c < 8) ? asw : adw;
    float s = 0.f;
#pragma unroll
    for (int j = 0; j < 8; ++j) s += W1[(size_t)k * HOUT + h * 8 + j] * wv[h * 8 + j];
    W1at[(size_t)c * WLD + k] = f2b(s);
}

// W2t[48][64] (cols>=40 zero) + uv[128]: u[c]=sum W2[c][cls]*asw2[cls], v likewise
__global__ __launch_bounds__(256) void w2conv_k(const float* __restrict__ W2, const float* __restrict__ asw,
                                                const float* __restrict__ adw, ushort* __restrict__ W2t,
                                                float* __restrict__ uv) {
    int idx = blockIdx.x * 256 + threadIdx.x;
    if (idx < 48 * HOUT) {
        int c = idx >> 6, k = idx & 63;
        W2t[idx] = (c < NCLS) ? f2b(W2[k * NCLS + c]) : 0;
    } else if (idx < 48 * HOUT + 128) {
        int c = idx - 48 * HOUT;
        const float* wv = (c < 64) ? asw : adw;
        int cc = c & 63;
        float s = 0.f;
        for (int cls = 0; cls < NCLS; ++cls) s += W2[cc * NCLS + cls] * wv[cls];
        uv[c] = s;
    }
}

// ---------------- Layer 1 GEMM (bf16 MFMA) + fused attention dots ----------------

__global__ __launch_bounds__(256) void gemm1_k(const float* __restrict__ x, const ushort* __restrict__ Wtg,
                                               const ushort* __restrict__ W1at, ushort* __restrict__ h1b,
                                               float* __restrict__ asd, int n) {
    __shared__ ushort Asd[128][40];
    int tid = threadIdx.x;
    int lane = tid & 63, wid = tid >> 6;
    int lr = lane & 15, lg = lane >> 4;
    int row0 = blockIdx.x * 128;
    f32x4 acc[2][4];
    f32x4 acca[2];
#pragma unroll
    for (int rt = 0; rt < 2; ++rt) {
        acca[rt] = (f32x4){0.f, 0.f, 0.f, 0.f};
#pragma unroll
        for (int ct = 0; ct < 4; ++ct) acc[rt][ct] = (f32x4){0.f, 0.f, 0.f, 0.f};
    }

    for (int k0 = 0; k0 < F_IN; k0 += 32) {
#pragma unroll
        for (int j = 0; j < 4; ++j) {
            int idx = tid + j * 256;
            int r = idx >> 3;
            int k4 = (idx & 7) << 2;
            int gr = row0 + r;
            float4 v = (gr < n) ? *(const float4*)&x[(size_t)gr * F_IN + k0 + k4]
                                : make_float4(0.f, 0.f, 0.f, 0.f);
            ushort4 b4 = make_ushort4(f2b(v.x), f2b(v.y), f2b(v.z), f2b(v.w));
            *(ushort4*)&Asd[r][k4] = b4;
        }
        __syncthreads();
        short8 af[2], bf[4];
#pragma unroll
        for (int rt = 0; rt < 2; ++rt)
            af[rt] = *(const short8*)&Asd[wid * 32 + rt * 16 + lr][lg * 8];
#pragma unroll
        for (int ct = 0; ct < 4; ++ct)
            bf[ct] = *(const short8*)&Wtg[(size_t)(ct * 16 + lr) * WLD + k0 + lg * 8];
        short8 bfa = *(const short8*)&W1at[(size_t)lr * WLD + k0 + lg * 8];
#pragma unroll
        for (int rt = 0; rt < 2; ++rt) {
#pragma unroll
            for (int ct = 0; ct < 4; ++ct)
                acc[rt][ct] = __builtin_amdgcn_mfma_f32_16x16x32_bf16(af[rt], bf[ct], acc[rt][ct], 0, 0, 0);
            acca[rt] = __builtin_amdgcn_mfma_f32_16x16x32_bf16(af[rt], bfa, acca[rt], 0, 0, 0);
        }
        __syncthreads();
    }
#pragma unroll
    for (int rt = 0; rt < 2; ++rt)
#pragma unroll
        for (int q = 0; q < 4; ++q) {
            int gr = row0 + wid * 32 + rt * 16 + lg * 4 + q;
            if (gr < n) {
#pragma unroll
                for (int ct = 0; ct < 4; ++ct)
                    h1b[(size_t)gr * HOUT + ct * 16 + lr] = f2b(acc[rt][ct][q]);
                asd[(size_t)gr * 16 + lr] = acca[rt][q];
            }
        }
}

// ---------------- layer-1 aggregation: 2 nodes/wave + fused as2/ad2 ----------------

__global__ __launch_bounds__(256) void l1agg_k(const ushort* __restrict__ h1b, const float* __restrict__ asd,
                                               const float* __restrict__ b1,
                                               const int* __restrict__ rowptr, const int* __restrict__ col,
                                               ushort* __restrict__ hactb, const float* __restrict__ uv,
                                               float* __restrict__ as2, float* __restrict__ ad2, int n) {
    __shared__ int2 pk_all[4][2 * 273 + 8];
    int wid = threadIdx.x >> 6, lane = threadIdx.x & 63;
    int nA = (blockIdx.x * 4 + wid) * 2;
    if (nA >= n) return;
    int nB = nA + 1;
    int na = lane >> 5, sl = lane & 31;
    int node = nA + na;
    bool nodev = node < n;
    int r0 = rowptr[nA];
    int r1 = rowptr[nA + 1];
    int r2 = (nB < n) ? rowptr[nB + 1] : r1;
    int degA = r1 - r0, degB = r2 - r1;
    int st  = na ? r1 : r0;
    int deg = na ? degB : degA;
    int2* pk = pk_all[wid];
    float e0, e1;

    if (degA <= 32 && degB <= 32) {
        bool v = nodev && (sl < deg);
        int s = 0;
        float4 a0 = make_float4(0.f, 0.f, 0.f, 0.f), a1 = a0;
        if (v) {
            s = col[st + sl];
            a0 = *(const float4*)&asd[s * 16];
            a1 = *(const float4*)&asd[s * 16 + 4];
        }
        float4 d0 = make_float4(0.f, 0.f, 0.f, 0.f), d1 = d0;
        if (nodev) {
            d0 = *(const float4*)&asd[node * 16 + 8];
            d1 = *(const float4*)&asd[node * 16 + 12];
        }
        float ea[8] = {a0.x + d0.x, a0.y + d0.y, a0.z + d0.z, a0.w + d0.w,
                       a1.x + d1.x, a1.y + d1.y, a1.z + d1.z, a1.w + d1.w};
#pragma unroll
        for (int h = 0; h < 8; ++h) {
            float ev = ea[h];
            float ee = v ? (ev >= 0.f ? ev : NEG * ev) : -1e30f;
            pk[na * 273 + h * 34 + sl] = make_int2(__float_as_int(ee), s);
        }
        __asm__ volatile("s_waitcnt lgkmcnt(0)" ::: "memory");
        __builtin_amdgcn_sched_barrier(0);
        {
            int t = lane & 3, h = (lane >> 2) & 7, na2 = lane >> 5;
            int base = na2 * 273 + h * 34;
            float e[8];
#pragma unroll
            for (int u = 0; u < 8; ++u) e[u] = __int_as_float(pk[base + t + 4 * u].x);
            float mx = e[0];
#pragma unroll
            for (int u = 1; u < 8; ++u) mx = fmaxf(mx, e[u]);
            mx = fmaxf(mx, __shfl_xor(mx, 1));
            mx = fmaxf(mx, __shfl_xor(mx, 2));
            float p[8], sm = 0.f;
#pragma unroll
            for (int u = 0; u < 8; ++u) { p[u] = __expf(e[u] - mx); sm += p[u]; }
            sm += __shfl_xor(sm, 1);
            sm += __shfl_xor(sm, 2);
            float inv = 1.f / (sm + 1e-16f);
#pragma unroll
            for (int u = 0; u < 8; ++u) pk[base + t + 4 * u].x = __float_as_int(p[u] * inv);
        }
        __asm__ volatile("s_waitcnt lgkmcnt(0)" ::: "memory");
        __builtin_amdgcn_sched_barrier(0);
        int pbase = na * 273 + (sl >> 2) * 34;
        float acc0 = 0.f, acc1 = 0.f;
        int mdeg = max(degA, degB);
        for (int g = 0; g * 8 < mdeg; ++g) {
#pragma unroll
            for (int jj = 0; jj < 8; ++jj) {
                int j = g * 8 + jj;
                int2 p2 = pk[pbase + j];
                float w = __int_as_float(p2.x);
                unsigned hv = *(const unsigned*)&h1b[(size_t)p2.y * HOUT + 2 * sl];
                acc0 += w * b2f_lo(hv);
                acc1 += w * b2f_hi(hv);
            }
        }
        float2 bb = *(const float2*)&b1[2 * sl];
        float o0 = acc0 + bb.x, o1 = acc1 + bb.y;
        e0 = o0 > 0.f ? o0 : expm1f(o0);
        e1 = o1 > 0.f ? o1 : expm1f(o1);
    } else {
        // rare fallback: serial online softmax per half
        int hd = sl >> 2;
        float ad = nodev ? asd[node * 16 + 8 + hd] : 0.f;
        float m = -1e30f, den = 0.f, a0 = 0.f, a1 = 0.f;
        int en = st + deg;
        for (int e = st; e < en; ++e) {
            int s = col[e];
            float ev = asd[s * 16 + hd] + ad;
            float ee = ev >= 0.f ? ev : NEG * ev;
            unsigned hv = *(const unsigned*)&h1b[(size_t)s * HOUT + 2 * sl];
            float mn = fmaxf(m, ee);
            float sc = __expf(m - mn), p = __expf(ee - mn);
            den = den * sc + p;
            a0 = a0 * sc + p * b2f_lo(hv);
            a1 = a1 * sc + p * b2f_hi(hv);
            m = mn;
        }
        float2 bb = *(const float2*)&b1[2 * sl];
        float o0 = a0 / (den + 1e-16f) + bb.x;
        float o1 = a1 / (den + 1e-16f) + bb.y;
        e0 = o0 > 0.f ? o0 : expm1f(o0);
        e1 = o1 > 0.f ? o1 : expm1f(o1);
    }
    // common epilogue: store hact, fused as2/ad2 = hact . u / hact . v
    unsigned op = (unsigned)f2b(e0) | ((unsigned)f2b(e1) << 16);
    if (nodev) *(unsigned*)&hactb[(size_t)node * HOUT + 2 * sl] = op;
    float2 uu = *(const float2*)&uv[2 * sl];
    float2 vv = *(const float2*)&uv[64 + 2 * sl];
    float tu = e0 * uu.x + e1 * uu.y;
    float tv = e0 * vv.x + e1 * vv.y;
    tu += __shfl_xor(tu, 1); tu += __shfl_xor(tu, 2); tu += __shfl_xor(tu, 4);
    tu += __shfl_xor(tu, 8); tu += __shfl_xor(tu, 16);
    tv += __shfl_xor(tv, 1); tv += __shfl_xor(tv, 2); tv += __shfl_xor(tv, 4);
    tv += __shfl_xor(tv, 8); tv += __shfl_xor(tv, 16);
    if (nodev && sl == 0) as2[node] = tu;
    if (nodev && sl == 1) ad2[node] = tv;
}

// ---------------- layer-2 GEMM (64->40): MFMA only ----------------

__global__ __launch_bounds__(256) void g2_k(const ushort* __restrict__ hactb, const ushort* __restrict__ W2t,
                                            ushort* __restrict__ h2b, int n) {
    int tid = threadIdx.x;
    int lane = tid & 63, wid = tid >> 6;
    int lr = lane & 15, lg = lane >> 4;
    int row0 = blockIdx.x * 64 + wid * 16;
    if (row0 >= n) return;
    int gr = row0 + lr;
    bool vr = gr < n;
    f32x4 acc[3];
#pragma unroll
    for (int ct = 0; ct < 3; ++ct) acc[ct] = (f32x4){0.f, 0.f, 0.f, 0.f};
    const short8 z8 = (short8){0, 0, 0, 0, 0, 0, 0, 0};
#pragma unroll
    for (int ks = 0; ks < 2; ++ks) {
        short8 af = vr ? *(const short8*)&hactb[(size_t)gr * HOUT + ks * 32 + lg * 8] : z8;
#pragma unroll
        for (int ct = 0; ct < 3; ++ct) {
            short8 bf = *(const short8*)&W2t[(ct * 16 + lr) * HOUT + ks * 32 + lg * 8];
            acc[ct] = __builtin_amdgcn_mfma_f32_16x16x32_bf16(af, bf, acc[ct], 0, 0, 0);
        }
    }
#pragma unroll
    for (int q = 0; q < 4; ++q) {
        int r = row0 + lg * 4 + q;
        if (r < n) {
#pragma unroll
            for (int ct = 0; ct < 3; ++ct) {
                int c = ct * 16 + lr;
                if (c < NCLS) h2b[(size_t)r * NCLS + c] = f2b(acc[ct][q]);
            }
        }
    }
}

// ---------------- layer-2 aggregation + log_softmax: 2 nodes/wave ----------------

__global__ __launch_bounds__(256) void l2agg_k(const ushort* __restrict__ h2b, const float* __restrict__ as2,
                                               const float* __restrict__ ad2, const float* __restrict__ b2,
                                               const int* __restrict__ rowptr, const int* __restrict__ col,
                                               float* __restrict__ out, int n) {
    __shared__ int2 pk_all[4][2 * 33 + 8];
    int wid = threadIdx.x >> 6, lane = threadIdx.x & 63;
    int nA = (blockIdx.x * 4 + wid) * 2;
    if (nA >= n) return;
    int nB = nA + 1;
    int na = lane >> 5, sl = lane & 31;
    int node = nA + na;
    bool nodev = node < n;
    int r0 = rowptr[nA];
    int r1 = rowptr[nA + 1];
    int r2 = (nB < n) ? rowptr[nB + 1] : r1;
    int degA = r1 - r0, degB = r2 - r1;
    int st  = na ? r1 : r0;
    int deg = na ? degB : degA;
    bool act = sl < 20;
    float z0, z1;

    if (degA <= 32 && degB <= 32) {
        int2* pk = pk_all[wid];
        bool v = nodev && (sl < deg);
        int s = 0; float av = 0.f;
        if (v) { s = col[st + sl]; av = as2[s]; }
        float ad = nodev ? ad2[node] : 0.f;
        float ev = av + ad;
        float ee = v ? (ev >= 0.f ? ev : NEG * ev) : -1e30f;
        float m = ee;
        m = fmaxf(m, __shfl_xor(m, 1)); m = fmaxf(m, __shfl_xor(m, 2));
        m = fmaxf(m, __shfl_xor(m, 4)); m = fmaxf(m, __shfl_xor(m, 8));
        m = fmaxf(m, __shfl_xor(m, 16));
        float p = __expf(ee - m);
        float d = p;
        d += __shfl_xor(d, 1); d += __shfl_xor(d, 2); d += __shfl_xor(d, 4);
        d += __shfl_xor(d, 8); d += __shfl_xor(d, 16);
        float w = p / (d + 1e-16f);
        pk[na * 33 + sl] = make_int2(__float_as_int(w), s);
        __asm__ volatile("s_waitcnt lgkmcnt(0)" ::: "memory");
        __builtin_amdgcn_sched_barrier(0);
        float acc0 = 0.f, acc1 = 0.f;
        int mdeg = max(degA, degB);
        for (int g = 0; g * 8 < mdeg; ++g) {
#pragma unroll
            for (int jj = 0; jj < 8; ++jj) {
                int j = g * 8 + jj;
                int2 p2 = pk[na * 33 + j];
                float wv = __int_as_float(p2.x);
                if (act) {
                    unsigned hv = *(const unsigned*)&h2b[(size_t)p2.y * NCLS + 2 * sl];
                    acc0 += wv * b2f_lo(hv);
                    acc1 += wv * b2f_hi(hv);
                }
            }
        }
        if (act) {
            float2 bb = *(const float2*)&b2[2 * sl];
            z0 = acc0 + bb.x; z1 = acc1 + bb.y;
        } else { z0 = z1 = -1e30f; }
    } else {
        float ad = nodev ? ad2[node] : 0.f;
        float m = -1e30f, den = 0.f, a0 = 0.f, a1 = 0.f;
        int en = st + deg;
        for (int e = st; e < en; ++e) {
            int s = col[e];
            float ev = as2[s] + ad;
            float ee = ev >= 0.f ? ev : NEG * ev;
            float mn = fmaxf(m, ee);
            float sc = __expf(m - mn), p = __expf(ee - mn);
            den = den * sc + p;
            if (act) {
                unsigned hv = *(const unsigned*)&h2b[(size_t)s * NCLS + 2 * sl];
                a0 = a0 * sc + p * b2f_lo(hv);
                a1 = a1 * sc + p * b2f_hi(hv);
            }
            m = mn;
        }
        if (act) {
            float2 bb = *(const float2*)&b2[2 * sl];
            z0 = a0 / (den + 1e-16f) + bb.x;
            z1 = a1 / (den + 1e-16f) + bb.y;
        } else { z0 = z1 = -1e30f; }
    }
    float zm = fmaxf(z0, z1);
    zm = fmaxf(zm, __shfl_xor(zm, 1)); zm = fmaxf(zm, __shfl_xor(zm, 2));
    zm = fmaxf(zm, __shfl_xor(zm, 4)); zm = fmaxf(zm, __shfl_xor(zm, 8));
    zm = fmaxf(zm, __shfl_xor(zm, 16));
    float ex = act ? (__expf(z0 - zm) + __expf(z1 - zm)) : 0.f;
    ex += __shfl_xor(ex, 1); ex += __shfl_xor(ex, 2); ex += __shfl_xor(ex, 4);
    ex += __shfl_xor(ex, 8); ex += __shfl_xor(ex, 16);
    float ls = logf(ex);
    if (act && nodev) {
        float2 o = make_float2(z0 - zm - ls, z1 - zm - ls);
        *(float2*)&out[(size_t)node * NCLS + 2 * sl] = o;
    }
}

// ---------------- host ----------------

extern "C" void kernel_launch(void* const* d_in, const int* in_sizes, int n_in,
                              void* d_out, int out_size, void* d_ws, size_t ws_size,
                              hipStream_t stream) {
    const float* x    = (const float*)d_in[0];
    const int*   ei   = (const int*)d_in[1];
    const float* W1   = (const float*)d_in[2];
    const float* asw1 = (const float*)d_in[3];
    const float* adw1 = (const float*)d_in[4];
    const float* b1   = (const float*)d_in[5];
    const float* W2   = (const float*)d_in[6];
    const float* asw2 = (const float*)d_in[7];
    const float* adw2 = (const float*)d_in[8];
    const float* b2   = (const float*)d_in[9];
    float* out = (float*)d_out;

    const int n = in_sizes[0] / F_IN;          // 100000
    const int E = in_sizes[1] / 2;             // 1600000
    const int Etot = E + n;
    const int nbuck = (n + DPB - 1) / DPB;     // 391
    const int npair = (n + 1) / 2;

    char* ws = (char*)d_ws;
    size_t off = 0;
    auto alloc = [&](size_t bytes) -> void* {
        void* p = ws + off;
        off = (off + bytes + 255) & ~(size_t)255;
        return p;
    };
    int*    gcur   = (int*)alloc((size_t)nbuck * 4);
    int*    bbase  = (int*)alloc((size_t)nbuck * 4);
    int*    rowptr = (int*)alloc((size_t)(n + 1) * 4);
    int*    col    = (int*)alloc((size_t)Etot * 4);
    int*    bkt    = (int*)alloc((size_t)nbuck * CAP * 4);           // 12.6 MB (packed)
    ushort* h1b    = (ushort*)alloc((size_t)n * HOUT * 2);           // 12.8 MB (reused as h2b)
    float*  asd    = (float*)alloc((size_t)n * 16 * 4);              // 6.4 MB (as|ad fused)
    ushort* hactb  = (ushort*)alloc((size_t)n * HOUT * 2);           // 12.8 MB
    float*  as2    = (float*)alloc((size_t)n * 4);
    float*  ad2    = (float*)alloc((size_t)n * 4);
    ushort* Wtg    = (ushort*)alloc((size_t)HOUT * WLD * 2);
    ushort* W1at   = (ushort*)alloc((size_t)16 * WLD * 2);
    ushort* W2t    = (ushort*)alloc((size_t)48 * HOUT * 2);
    float*  uv     = (float*)alloc(128 * 4);
    ushort* h2b = h1b;   // h1b dead after l1agg

    init_k<<<(nbuck + 511) / 512, 512, 0, stream>>>(gcur, nbuck);
    passA_k<<<(Etot + 256 * EPT - 1) / (256 * EPT), 256, 0, stream>>>(ei, gcur, bkt, E, Etot, nbuck);
    bscan_k<<<1, 512, 0, stream>>>(gcur, bbase, rowptr, nbuck, n, Etot);
    passB_k<<<nbuck, 256, 0, stream>>>(bkt, gcur, bbase, rowptr, col, n);

    wconv_k<<<(F_IN * HOUT + 255) / 256, 256, 0, stream>>>(W1, Wtg);
    wprep_k<<<(16 * F_IN + 255) / 256, 256, 0, stream>>>(W1, asw1, adw1, W1at);
    w2conv_k<<<(48 * HOUT + 128 + 255) / 256, 256, 0, stream>>>(W2, asw2, adw2, W2t, uv);

    gemm1_k<<<(n + 127) / 128, 256, 0, stream>>>(x, Wtg, W1at, h1b, asd, n);
    l1agg_k<<<(npair + 3) / 4, 256, 0, stream>>>(h1b, asd, b1, rowptr, col, hactb, uv, as2, ad2, n);
    g2_k<<<(n + 63) / 64, 256, 0, stream>>>(hactb, W2t, h2b, n);
    l2agg_k<<<(npair + 3) / 4, 256, 0, stream>>>(h2b, as2, ad2, b2, rowptr, col, out, n);
}

// Round 9
// 251.574 us; speedup vs baseline: 1.1593x; 1.1593x over previous
//
#include <hip/hip_runtime.h>
#include <hip/hip_bf16.h>
#include <math.h>

#define F_IN 512
#define HOUT 64      // HEADS*C1
#define HEADS 8
#define C1 8
#define NCLS 40
#define NEG 0.2f

#define DPB 256            // dsts per bucket
#define CAP 8064           // staging capacity per bucket
#define EPT 32             // edges per thread in passA
#define WLD 520            // padded K-stride of transposed bf16 W1

typedef __attribute__((ext_vector_type(8))) short short8;
typedef __attribute__((ext_vector_type(4))) float f32x4;

__device__ __forceinline__ ushort f2b(float f) {
    union { float f; unsigned u; } v; v.f = f;
    unsigned r = (v.u + 0x7FFFu + ((v.u >> 16) & 1u)) >> 16;   // RNE
    return (ushort)r;
}
__device__ __forceinline__ float b2f(ushort b) {
    union { unsigned u; float f; } v; v.u = ((unsigned)b) << 16;
    return v.f;
}
__device__ __forceinline__ float b2f_lo(unsigned u) { union { unsigned u; float f; } v; v.u = u << 16; return v.f; }
__device__ __forceinline__ float b2f_hi(unsigned u) { union { unsigned u; float f; } v; v.u = u & 0xFFFF0000u; return v.f; }

// ---------------- prep: init ∥ wconv ∥ w2conv (block-fused) ----------------

__global__ __launch_bounds__(256) void prep_k(const float* __restrict__ W1, const float* __restrict__ W2,
                                              int* __restrict__ gcur, ushort* __restrict__ Wtg,
                                              ushort* __restrict__ W2t, int nbuck) {
    int bid = blockIdx.x, t = threadIdx.x;
    if (bid < 128) {                       // wconv: W1 -> Wtg[c][k] bf16, padded
        int idx = bid * 256 + t;
        int k = idx >> 6, c = idx & 63;
        Wtg[(size_t)c * WLD + k] = f2b(W1[idx]);
    } else if (bid < 140) {                // w2conv: W2 -> W2t[48][64] (cols>=40 zero)
        int idx = (bid - 128) * 256 + t;
        int c = idx >> 6, k = idx & 63;
        W2t[idx] = (c < NCLS) ? f2b(W2[k * NCLS + c]) : 0;
    } else {                               // init gcur
        int b = (bid - 140) * 256 + t;
        if (b < nbuck) gcur[b] = b * CAP;
    }
}

// ---------------- work1: gemm1 ∥ passA (block-fused) ----------------

__device__ void gemm1_body(int bid, const float* __restrict__ x, const ushort* __restrict__ Wtg,
                           ushort* __restrict__ h1b, int n, ushort Asd[128][40]) {
    int tid = threadIdx.x;
    int lane = tid & 63, wid = tid >> 6;
    int lr = lane & 15, lg = lane >> 4;
    int row0 = bid * 128;
    f32x4 acc[2][4];
#pragma unroll
    for (int rt = 0; rt < 2; ++rt)
#pragma unroll
        for (int ct = 0; ct < 4; ++ct) acc[rt][ct] = (f32x4){0.f, 0.f, 0.f, 0.f};

    for (int k0 = 0; k0 < F_IN; k0 += 32) {
#pragma unroll
        for (int j = 0; j < 4; ++j) {
            int idx = tid + j * 256;
            int r = idx >> 3;
            int k4 = (idx & 7) << 2;
            int gr = row0 + r;
            float4 v = (gr < n) ? *(const float4*)&x[(size_t)gr * F_IN + k0 + k4]
                                : make_float4(0.f, 0.f, 0.f, 0.f);
            ushort4 b4 = make_ushort4(f2b(v.x), f2b(v.y), f2b(v.z), f2b(v.w));
            *(ushort4*)&Asd[r][k4] = b4;
        }
        __syncthreads();
        short8 af[2], bf[4];
#pragma unroll
        for (int rt = 0; rt < 2; ++rt)
            af[rt] = *(const short8*)&Asd[wid * 32 + rt * 16 + lr][lg * 8];
#pragma unroll
        for (int ct = 0; ct < 4; ++ct)
            bf[ct] = *(const short8*)&Wtg[(size_t)(ct * 16 + lr) * WLD + k0 + lg * 8];
#pragma unroll
        for (int rt = 0; rt < 2; ++rt)
#pragma unroll
            for (int ct = 0; ct < 4; ++ct)
                acc[rt][ct] = __builtin_amdgcn_mfma_f32_16x16x32_bf16(af[rt], bf[ct], acc[rt][ct], 0, 0, 0);
        __syncthreads();
    }
#pragma unroll
    for (int rt = 0; rt < 2; ++rt)
#pragma unroll
        for (int q = 0; q < 4; ++q) {
            int gr = row0 + wid * 32 + rt * 16 + lg * 4 + q;
            if (gr < n) {
#pragma unroll
                for (int ct = 0; ct < 4; ++ct)
                    h1b[(size_t)gr * HOUT + ct * 16 + lr] = f2b(acc[rt][ct][q]);
            }
        }
}

__device__ void passA_body(int bid, const int* __restrict__ ei, int* __restrict__ gcur,
                           int* __restrict__ bkt, int E, int Etot, int nbuck,
                           int* hist, int* lbase) {
    int t = threadIdx.x;
    int base_e = bid * (256 * EPT);
    for (int j = t; j < 512; j += 256) hist[j] = 0;
    __syncthreads();
    for (int j = 0; j < EPT; ++j) {
        int idx = base_e + j * 256 + t;
        if (idx < Etot) {
            int d = (idx < E) ? ei[E + idx] : (idx - E);
            atomicAdd(&hist[d >> 8], 1);
        }
    }
    __syncthreads();
    for (int j = t; j < nbuck; j += 256) {
        int c = hist[j];
        lbase[j] = c ? atomicAdd(&gcur[j], c) : 0;
    }
    __syncthreads();
    for (int j = t; j < 512; j += 256) hist[j] = 0;
    __syncthreads();
    for (int j = 0; j < EPT; ++j) {
        int idx = base_e + j * 256 + t;
        if (idx < Etot) {
            int s, d;
            if (idx < E) { s = ei[idx]; d = ei[E + idx]; } else { s = idx - E; d = idx - E; }
            int b = d >> 8;
            int slot = atomicAdd(&hist[b], 1);
            bkt[lbase[b] + slot] = (s << 8) | (d & 255);   // packed 4B
        }
    }
}

__global__ __launch_bounds__(256) void work1_k(const float* __restrict__ x, const ushort* __restrict__ Wtg,
                                               ushort* __restrict__ h1b, int n,
                                               const int* __restrict__ ei, int* __restrict__ gcur,
                                               int* __restrict__ bkt, int E, int Etot, int nbuck, int g1) {
    __shared__ ushort Asd[128][40];
    __shared__ int hist[512];
    __shared__ int lbase[512];
    if ((int)blockIdx.x < g1) gemm1_body(blockIdx.x, x, Wtg, h1b, n, Asd);
    else passA_body(blockIdx.x - g1, ei, gcur, bkt, E, Etot, nbuck, hist, lbase);
}

// ---------------- bscan ----------------

__global__ __launch_bounds__(512) void bscan_k(const int* __restrict__ gcur, int* __restrict__ bbase,
                                               int* __restrict__ rowptr, int nbuck, int n, int Etot) {
    __shared__ int wsum[8];
    int t = threadIdx.x;
    int v = (t < nbuck) ? gcur[t] - t * CAP : 0;
    int lane = t & 63, w = t >> 6;
    int ss = v;
#pragma unroll
    for (int off = 1; off < 64; off <<= 1) { int t2 = __shfl_up(ss, off); if (lane >= off) ss += t2; }
    if (lane == 63) wsum[w] = ss;
    __syncthreads();
    int woff = 0;
    for (int j = 0; j < w; ++j) woff += wsum[j];
    if (t < nbuck) bbase[t] = woff + ss - v;
    if (t == 0) rowptr[n] = Etot;
}

// ---------------- work2: passB ∥ att1 (block-fused) ----------------

__device__ void passB_body(int b, const int* __restrict__ bkt, const int* __restrict__ gcur,
                           const int* __restrict__ bbase, int* __restrict__ rowptr,
                           int* __restrict__ col, int n, int* hist, int* lcur, int* wsum) {
    int t = threadIdx.x;
    int cnt = gcur[b] - b * CAP;
    int base = bbase[b];
    int d0 = b * DPB;
    int ndst = min(DPB, n - d0);
    const int* src = bkt + (size_t)b * CAP;
    hist[t] = 0;
    __syncthreads();
    for (int e = t; e < cnt; e += 256) {
        atomicAdd(&hist[src[e] & 255], 1);
    }
    __syncthreads();
    int v = hist[t];
    int lane = t & 63, w = t >> 6;
    int ss = v;
#pragma unroll
    for (int off = 1; off < 64; off <<= 1) { int t2 = __shfl_up(ss, off); if (lane >= off) ss += t2; }
    if (lane == 63) wsum[w] = ss;
    __syncthreads();
    int woff = 0;
    for (int j = 0; j < w; ++j) woff += wsum[j];
    int excl = woff + ss - v;
    if (t < ndst) rowptr[d0 + t] = base + excl;
    lcur[t] = excl;
    __syncthreads();
    for (int e = t; e < cnt; e += 256) {
        int u = src[e];
        int pos = atomicAdd(&lcur[u & 255], 1);
        col[base + pos] = (int)((unsigned)u >> 8);
    }
}

__device__ void att1_body(int bid, const ushort* __restrict__ h1b, const float* __restrict__ asw,
                          const float* __restrict__ adw, float* __restrict__ as1,
                          float* __restrict__ ad1, int n) {
    int t = bid * 256 + threadIdx.x;
    if (t >= n * HEADS) return;
    int hd = t & 7;
    const ushort* hp = h1b + (size_t)(t >> 3) * HOUT + hd * C1;
    short8 hv = *(const short8*)hp;
    float4 a0 = *(const float4*)(asw + hd * C1), a1 = *(const float4*)(asw + hd * C1 + 4);
    float4 d0 = *(const float4*)(adw + hd * C1), d1 = *(const float4*)(adw + hd * C1 + 4);
    float h0 = b2f((ushort)hv[0]), h1 = b2f((ushort)hv[1]), h2 = b2f((ushort)hv[2]), h3 = b2f((ushort)hv[3]);
    float h4 = b2f((ushort)hv[4]), h5 = b2f((ushort)hv[5]), h6 = b2f((ushort)hv[6]), h7 = b2f((ushort)hv[7]);
    as1[t] = h0*a0.x + h1*a0.y + h2*a0.z + h3*a0.w + h4*a1.x + h5*a1.y + h6*a1.z + h7*a1.w;
    ad1[t] = h0*d0.x + h1*d0.y + h2*d0.z + h3*d0.w + h4*d1.x + h5*d1.y + h6*d1.z + h7*d1.w;
}

__global__ __launch_bounds__(256) void work2_k(const int* __restrict__ bkt, const int* __restrict__ gcur,
                                               const int* __restrict__ bbase, int* __restrict__ rowptr,
                                               int* __restrict__ col, int n,
                                               const ushort* __restrict__ h1b, const float* __restrict__ asw,
                                               const float* __restrict__ adw, float* __restrict__ as1,
                                               float* __restrict__ ad1, int gpb) {
    __shared__ int hist[DPB];
    __shared__ int lcur[DPB];
    __shared__ int wsum[4];
    if ((int)blockIdx.x < gpb) passB_body(blockIdx.x, bkt, gcur, bbase, rowptr, col, n, hist, lcur, wsum);
    else att1_body(blockIdx.x - gpb, h1b, asw, adw, as1, ad1, n);
}

// ---------------- layer-1 aggregation: 2 nodes/wave, 2 channels/lane ----------------

__global__ __launch_bounds__(256) void l1agg_k(const ushort* __restrict__ h1b, const float* __restrict__ as1,
                                               const float* __restrict__ ad1, const float* __restrict__ b1,
                                               const int* __restrict__ rowptr, const int* __restrict__ col,
                                               ushort* __restrict__ hactb, int n) {
    __shared__ int2 pk_all[4][2 * 273];
    int wid = threadIdx.x >> 6, lane = threadIdx.x & 63;
    int nA = (blockIdx.x * 4 + wid) * 2;
    if (nA >= n) return;
    int nB = nA + 1;
    int na = lane >> 5, sl = lane & 31;
    int node = nA + na;
    bool nodev = node < n;
    int r0 = rowptr[nA];
    int r1 = rowptr[nA + 1];
    int r2 = (nB < n) ? rowptr[nB + 1] : r1;
    int degA = r1 - r0, degB = r2 - r1;
    int st  = na ? r1 : r0;
    int deg = na ? degB : degA;
    int2* pk = pk_all[wid];

    if (degA <= 32 && degB <= 32) {
        bool v = nodev && (sl < deg);
        int s = 0;
        float4 a0 = make_float4(0.f, 0.f, 0.f, 0.f), a1 = a0;
        if (v) {
            s = col[st + sl];
            a0 = *(const float4*)&as1[s * 8];
            a1 = *(const float4*)&as1[s * 8 + 4];
        }
        float4 d0 = make_float4(0.f, 0.f, 0.f, 0.f), d1 = d0;
        if (nodev) {
            d0 = *(const float4*)&ad1[node * 8];
            d1 = *(const float4*)&ad1[node * 8 + 4];
        }
        float ea[8] = {a0.x + d0.x, a0.y + d0.y, a0.z + d0.z, a0.w + d0.w,
                       a1.x + d1.x, a1.y + d1.y, a1.z + d1.z, a1.w + d1.w};
#pragma unroll
        for (int h = 0; h < 8; ++h) {
            float e0 = ea[h];
            float ee = v ? (e0 >= 0.f ? e0 : NEG * e0) : -1e30f;
            pk[na * 273 + h * 34 + sl] = make_int2(__float_as_int(ee), s);
        }
        __asm__ volatile("s_waitcnt lgkmcnt(0)" ::: "memory");
        __builtin_amdgcn_sched_barrier(0);
        {
            int t = lane & 3, h = (lane >> 2) & 7, na2 = lane >> 5;
            int base = na2 * 273 + h * 34;
            float e[8];
#pragma unroll
            for (int u = 0; u < 8; ++u) e[u] = __int_as_float(pk[base + t + 4 * u].x);
            float mx = e[0];
#pragma unroll
            for (int u = 1; u < 8; ++u) mx = fmaxf(mx, e[u]);
            mx = fmaxf(mx, __shfl_xor(mx, 1));
            mx = fmaxf(mx, __shfl_xor(mx, 2));
            float p[8], sm = 0.f;
#pragma unroll
            for (int u = 0; u < 8; ++u) { p[u] = __expf(e[u] - mx); sm += p[u]; }
            sm += __shfl_xor(sm, 1);
            sm += __shfl_xor(sm, 2);
            float inv = 1.f / (sm + 1e-16f);
#pragma unroll
            for (int u = 0; u < 8; ++u) pk[base + t + 4 * u].x = __float_as_int(p[u] * inv);
        }
        __asm__ volatile("s_waitcnt lgkmcnt(0)" ::: "memory");
        __builtin_amdgcn_sched_barrier(0);
        int pbase = na * 273 + (sl >> 2) * 34;
        float acc0 = 0.f, acc1 = 0.f;
        int mdeg = max(degA, degB);
        for (int g = 0; g * 4 < mdeg; ++g) {
#pragma unroll
            for (int jj = 0; jj < 4; ++jj) {
                int j = g * 4 + jj;
                int2 p2 = pk[pbase + j];
                float w = __int_as_float(p2.x);
                unsigned hv = *(const unsigned*)&h1b[(size_t)p2.y * HOUT + 2 * sl];
                acc0 += w * b2f_lo(hv);
                acc1 += w * b2f_hi(hv);
            }
        }
        float2 bb = *(const float2*)&b1[2 * sl];
        float o0 = acc0 + bb.x, o1 = acc1 + bb.y;
        float e0 = o0 > 0.f ? o0 : expm1f(o0);
        float e1 = o1 > 0.f ? o1 : expm1f(o1);
        unsigned op = (unsigned)f2b(e0) | ((unsigned)f2b(e1) << 16);
        if (nodev) *(unsigned*)&hactb[(size_t)node * HOUT + 2 * sl] = op;
    } else {
        // rare fallback: serial online softmax per half, 2 channels per lane
        int hd = sl >> 2;
        float ad = nodev ? ad1[node * 8 + hd] : 0.f;
        float m = -1e30f, den = 0.f, a0 = 0.f, a1 = 0.f;
        int en = st + deg;
        for (int e = st; e < en; ++e) {
            int s = col[e];
            float e0 = as1[s * 8 + hd] + ad;
            float ee = e0 >= 0.f ? e0 : NEG * e0;
            unsigned hv = *(const unsigned*)&h1b[(size_t)s * HOUT + 2 * sl];
            float mn = fmaxf(m, ee);
            float sc = __expf(m - mn), p = __expf(ee - mn);
            den = den * sc + p;
            a0 = a0 * sc + p * b2f_lo(hv);
            a1 = a1 * sc + p * b2f_hi(hv);
            m = mn;
        }
        float2 bb = *(const float2*)&b1[2 * sl];
        float o0 = a0 / (den + 1e-16f) + bb.x;
        float o1 = a1 / (den + 1e-16f) + bb.y;
        float e0 = o0 > 0.f ? o0 : expm1f(o0);
        float e1 = o1 > 0.f ? o1 : expm1f(o1);
        unsigned op = (unsigned)f2b(e0) | ((unsigned)f2b(e1) << 16);
        if (nodev) *(unsigned*)&hactb[(size_t)node * HOUT + 2 * sl] = op;
    }
}

// ---------------- layer-2 GEMM (64->40) + attention dots: MFMA, no LDS ----------------

__global__ __launch_bounds__(256) void g2_k(const ushort* __restrict__ hactb, const ushort* __restrict__ W2t,
                                            const float* __restrict__ asw, const float* __restrict__ adw,
                                            ushort* __restrict__ h2b, float* __restrict__ as2,
                                            float* __restrict__ ad2, int n) {
    int tid = threadIdx.x;
    int lane = tid & 63, wid = tid >> 6;
    int lr = lane & 15, lg = lane >> 4;
    int row0 = blockIdx.x * 64 + wid * 16;
    if (row0 >= n) return;
    int gr = row0 + lr;
    bool vr = gr < n;
    f32x4 acc[3];
#pragma unroll
    for (int ct = 0; ct < 3; ++ct) acc[ct] = (f32x4){0.f, 0.f, 0.f, 0.f};
    const short8 z8 = (short8){0, 0, 0, 0, 0, 0, 0, 0};
#pragma unroll
    for (int ks = 0; ks < 2; ++ks) {
        short8 af = vr ? *(const short8*)&hactb[(size_t)gr * HOUT + ks * 32 + lg * 8] : z8;
#pragma unroll
        for (int ct = 0; ct < 3; ++ct) {
            short8 bf = *(const short8*)&W2t[(ct * 16 + lr) * HOUT + ks * 32 + lg * 8];
            acc[ct] = __builtin_amdgcn_mfma_f32_16x16x32_bf16(af, bf, acc[ct], 0, 0, 0);
        }
    }
    float av4[4], dv4[4];
#pragma unroll
    for (int q = 0; q < 4; ++q) {
        int r = row0 + lg * 4 + q;
        bool vw = r < n;
        float av = 0.f, dv = 0.f;
#pragma unroll
        for (int ct = 0; ct < 3; ++ct) {
            int c = ct * 16 + lr;
            if (c < NCLS) {
                float o = acc[ct][q];
                av += o * asw[c];
                dv += o * adw[c];
                if (vw) h2b[(size_t)r * NCLS + c] = f2b(o);
            }
        }
        av += __shfl_xor(av, 1); av += __shfl_xor(av, 2); av += __shfl_xor(av, 4); av += __shfl_xor(av, 8);
        dv += __shfl_xor(dv, 1); dv += __shfl_xor(dv, 2); dv += __shfl_xor(dv, 4); dv += __shfl_xor(dv, 8);
        av4[q] = av; dv4[q] = dv;
    }
#pragma unroll
    for (int q = 0; q < 4; ++q) {
        int r = row0 + lg * 4 + q;
        if (lr == q && r < n) as2[r] = av4[q];
        if (lr == 8 + q && r < n) ad2[r] = dv4[q];
    }
}

// ---------------- layer-2 aggregation + log_softmax: 2 nodes/wave ----------------

__global__ __launch_bounds__(256) void l2agg_k(const ushort* __restrict__ h2b, const float* __restrict__ as2,
                                               const float* __restrict__ ad2, const float* __restrict__ b2,
                                               const int* __restrict__ rowptr, const int* __restrict__ col,
                                               float* __restrict__ out, int n) {
    __shared__ int2 pk_all[4][2 * 33];
    int wid = threadIdx.x >> 6, lane = threadIdx.x & 63;
    int nA = (blockIdx.x * 4 + wid) * 2;
    if (nA >= n) return;
    int nB = nA + 1;
    int na = lane >> 5, sl = lane & 31;
    int node = nA + na;
    bool nodev = node < n;
    int r0 = rowptr[nA];
    int r1 = rowptr[nA + 1];
    int r2 = (nB < n) ? rowptr[nB + 1] : r1;
    int degA = r1 - r0, degB = r2 - r1;
    int st  = na ? r1 : r0;
    int deg = na ? degB : degA;
    bool act = sl < 20;
    float z0, z1;

    if (degA <= 32 && degB <= 32) {
        int2* pk = pk_all[wid];
        bool v = nodev && (sl < deg);
        int s = 0; float av = 0.f;
        if (v) { s = col[st + sl]; av = as2[s]; }
        float ad = nodev ? ad2[node] : 0.f;
        float e0 = av + ad;
        float ee = v ? (e0 >= 0.f ? e0 : NEG * e0) : -1e30f;
        float m = ee;
        m = fmaxf(m, __shfl_xor(m, 1)); m = fmaxf(m, __shfl_xor(m, 2));
        m = fmaxf(m, __shfl_xor(m, 4)); m = fmaxf(m, __shfl_xor(m, 8));
        m = fmaxf(m, __shfl_xor(m, 16));
        float p = __expf(ee - m);
        float d = p;
        d += __shfl_xor(d, 1); d += __shfl_xor(d, 2); d += __shfl_xor(d, 4);
        d += __shfl_xor(d, 8); d += __shfl_xor(d, 16);
        float w = p / (d + 1e-16f);
        pk[na * 33 + sl] = make_int2(__float_as_int(w), s);
        __asm__ volatile("s_waitcnt lgkmcnt(0)" ::: "memory");
        __builtin_amdgcn_sched_barrier(0);
        float acc0 = 0.f, acc1 = 0.f;
        int mdeg = max(degA, degB);
        for (int g = 0; g * 4 < mdeg; ++g) {
#pragma unroll
            for (int jj = 0; jj < 4; ++jj) {
                int j = g * 4 + jj;
                int2 p2 = pk[na * 33 + j];
                float wv = __int_as_float(p2.x);
                if (act) {
                    unsigned hv = *(const unsigned*)&h2b[(size_t)p2.y * NCLS + 2 * sl];
                    acc0 += wv * b2f_lo(hv);
                    acc1 += wv * b2f_hi(hv);
                }
            }
        }
        if (act) {
            float2 bb = *(const float2*)&b2[2 * sl];
            z0 = acc0 + bb.x; z1 = acc1 + bb.y;
        } else { z0 = z1 = -1e30f; }
    } else {
        float ad = nodev ? ad2[node] : 0.f;
        float m = -1e30f, den = 0.f, a0 = 0.f, a1 = 0.f;
        int en = st + deg;
        for (int e = st; e < en; ++e) {
            int s = col[e];
            float e0 = as2[s] + ad;
            float ee = e0 >= 0.f ? e0 : NEG * e0;
            float mn = fmaxf(m, ee);
            float sc = __expf(m - mn), p = __expf(ee - mn);
            den = den * sc + p;
            if (act) {
                unsigned hv = *(const unsigned*)&h2b[(size_t)s * NCLS + 2 * sl];
                a0 = a0 * sc + p * b2f_lo(hv);
                a1 = a1 * sc + p * b2f_hi(hv);
            }
            m = mn;
        }
        if (act) {
            float2 bb = *(const float2*)&b2[2 * sl];
            z0 = a0 / (den + 1e-16f) + bb.x;
            z1 = a1 / (den + 1e-16f) + bb.y;
        } else { z0 = z1 = -1e30f; }
    }
    float zm = fmaxf(z0, z1);
    zm = fmaxf(zm, __shfl_xor(zm, 1)); zm = fmaxf(zm, __shfl_xor(zm, 2));
    zm = fmaxf(zm, __shfl_xor(zm, 4)); zm = fmaxf(zm, __shfl_xor(zm, 8));
    zm = fmaxf(zm, __shfl_xor(zm, 16));
    float ex = act ? (__expf(z0 - zm) + __expf(z1 - zm)) : 0.f;
    ex += __shfl_xor(ex, 1); ex += __shfl_xor(ex, 2); ex += __shfl_xor(ex, 4);
    ex += __shfl_xor(ex, 8); ex += __shfl_xor(ex, 16);
    float ls = logf(ex);
    if (act && nodev) {
        float2 o = make_float2(z0 - zm - ls, z1 - zm - ls);
        *(float2*)&out[(size_t)node * NCLS + 2 * sl] = o;
    }
}

// ---------------- host ----------------

extern "C" void kernel_launch(void* const* d_in, const int* in_sizes, int n_in,
                              void* d_out, int out_size, void* d_ws, size_t ws_size,
                              hipStream_t stream) {
    const float* x    = (const float*)d_in[0];
    const int*   ei   = (const int*)d_in[1];
    const float* W1   = (const float*)d_in[2];
    const float* asw1 = (const float*)d_in[3];
    const float* adw1 = (const float*)d_in[4];
    const float* b1   = (const float*)d_in[5];
    const float* W2   = (const float*)d_in[6];
    const float* asw2 = (const float*)d_in[7];
    const float* adw2 = (const float*)d_in[8];
    const float* b2   = (const float*)d_in[9];
    float* out = (float*)d_out;

    const int n = in_sizes[0] / F_IN;          // 100000
    const int E = in_sizes[1] / 2;             // 1600000
    const int Etot = E + n;
    const int nbuck = (n + DPB - 1) / DPB;     // 391
    const int npair = (n + 1) / 2;

    char* ws = (char*)d_ws;
    size_t off = 0;
    auto alloc = [&](size_t bytes) -> void* {
        void* p = ws + off;
        off = (off + bytes + 255) & ~(size_t)255;
        return p;
    };
    int*    gcur   = (int*)alloc((size_t)nbuck * 4);
    int*    bbase  = (int*)alloc((size_t)nbuck * 4);
    int*    rowptr = (int*)alloc((size_t)(n + 1) * 4);
    int*    col    = (int*)alloc((size_t)Etot * 4);
    int*    bkt    = (int*)alloc((size_t)nbuck * CAP * 4);           // 12.6 MB (packed 4B)
    ushort* h1b    = (ushort*)alloc((size_t)n * HOUT * 2);           // 12.8 MB (reused as h2b)
    float*  as1    = (float*)alloc((size_t)n * HEADS * 4);
    float*  ad1    = (float*)alloc((size_t)n * HEADS * 4);
    ushort* hactb  = (ushort*)alloc((size_t)n * HOUT * 2);           // 12.8 MB
    ushort* Wtg    = (ushort*)alloc((size_t)HOUT * WLD * 2);
    ushort* W2t    = (ushort*)alloc((size_t)48 * HOUT * 2);
    ushort* h2b = h1b;   // h1b dead after l1agg
    float*  as2 = (float*)(h1b + (size_t)n * NCLS);
    float*  ad2 = as2 + n;

    const int g1 = (n + 127) / 128;                       // gemm1 blocks
    const int gpa = (Etot + 256 * EPT - 1) / (256 * EPT); // passA blocks
    const int gpb = nbuck;                                // passB blocks
    const int gat = (n * HEADS + 255) / 256;              // att1 blocks

    prep_k<<<142, 256, 0, stream>>>(W1, W2, gcur, Wtg, W2t, nbuck);
    work1_k<<<g1 + gpa, 256, 0, stream>>>(x, Wtg, h1b, n, ei, gcur, bkt, E, Etot, nbuck, g1);
    bscan_k<<<1, 512, 0, stream>>>(gcur, bbase, rowptr, nbuck, n, Etot);
    work2_k<<<gpb + gat, 256, 0, stream>>>(bkt, gcur, bbase, rowptr, col, n,
                                           h1b, asw1, adw1, as1, ad1, gpb);
    l1agg_k<<<(npair + 3) / 4, 256, 0, stream>>>(h1b, as1, ad1, b1, rowptr, col, hactb, n);
    g2_k<<<(n + 63) / 64, 256, 0, stream>>>(hactb, W2t, asw2, adw2, h2b, as2, ad2, n);
    l2agg_k<<<(npair + 3) / 4, 256, 0, stream>>>(h2b, as2, ad2, b2, rowptr, col, out, n);
}

// Round 10
// 233.695 us; speedup vs baseline: 1.2480x; 1.0765x over previous
//
#include <hip/hip_runtime.h>
#include <hip/hip_bf16.h>
#include <math.h>

#define F_IN 512
#define HOUT 64      // HEADS*C1
#define HEADS 8
#define C1 8
#define NCLS 40
#define NEG 0.2f

#define DPB 256            // dsts per bucket
#define CAP 8064           // staging capacity per bucket
#define EPT 32             // edges per thread in passA
#define WLD 520            // padded K-stride of transposed bf16 W1

typedef __attribute__((ext_vector_type(8))) short short8;
typedef __attribute__((ext_vector_type(4))) float f32x4;

__device__ __forceinline__ ushort f2b(float f) {
    union { float f; unsigned u; } v; v.f = f;
    unsigned r = (v.u + 0x7FFFu + ((v.u >> 16) & 1u)) >> 16;   // RNE
    return (ushort)r;
}
__device__ __forceinline__ float b2f(ushort b) {
    union { unsigned u; float f; } v; v.u = ((unsigned)b) << 16;
    return v.f;
}
__device__ __forceinline__ float b2f_lo(unsigned u) { union { unsigned u; float f; } v; v.u = u << 16; return v.f; }
__device__ __forceinline__ float b2f_hi(unsigned u) { union { unsigned u; float f; } v; v.u = u & 0xFFFF0000u; return v.f; }

// ---------------- prep: init ∥ wconv ∥ w2conv (block-fused) ----------------

__global__ __launch_bounds__(256) void prep_k(const float* __restrict__ W1, const float* __restrict__ W2,
                                              int* __restrict__ gcur, ushort* __restrict__ Wtg,
                                              ushort* __restrict__ W2t, int nbuck) {
    int bid = blockIdx.x, t = threadIdx.x;
    if (bid < 128) {                       // wconv: W1 -> Wtg[c][k] bf16, padded
        int idx = bid * 256 + t;
        int k = idx >> 6, c = idx & 63;
        Wtg[(size_t)c * WLD + k] = f2b(W1[idx]);
    } else if (bid < 140) {                // w2conv: W2 -> W2t[48][64] (cols>=40 zero)
        int idx = (bid - 128) * 256 + t;
        int c = idx >> 6, k = idx & 63;
        W2t[idx] = (c < NCLS) ? f2b(W2[k * NCLS + c]) : 0;
    } else {                               // init gcur
        int b = (bid - 140) * 256 + t;
        if (b < nbuck) gcur[b] = b * CAP;
    }
}

// ---------------- work1: gemm1 ∥ passA (block-fused) ----------------

__device__ void gemm1_body(int bid, const float* __restrict__ x, const ushort* __restrict__ Wtg,
                           ushort* __restrict__ h1b, int n, ushort Asd[128][40]) {
    int tid = threadIdx.x;
    int lane = tid & 63, wid = tid >> 6;
    int lr = lane & 15, lg = lane >> 4;
    int row0 = bid * 128;
    f32x4 acc[2][4];
#pragma unroll
    for (int rt = 0; rt < 2; ++rt)
#pragma unroll
        for (int ct = 0; ct < 4; ++ct) acc[rt][ct] = (f32x4){0.f, 0.f, 0.f, 0.f};

    for (int k0 = 0; k0 < F_IN; k0 += 32) {
#pragma unroll
        for (int j = 0; j < 4; ++j) {
            int idx = tid + j * 256;
            int r = idx >> 3;
            int k4 = (idx & 7) << 2;
            int gr = row0 + r;
            float4 v = (gr < n) ? *(const float4*)&x[(size_t)gr * F_IN + k0 + k4]
                                : make_float4(0.f, 0.f, 0.f, 0.f);
            ushort4 b4 = make_ushort4(f2b(v.x), f2b(v.y), f2b(v.z), f2b(v.w));
            *(ushort4*)&Asd[r][k4] = b4;
        }
        __syncthreads();
        short8 af[2], bf[4];
#pragma unroll
        for (int rt = 0; rt < 2; ++rt)
            af[rt] = *(const short8*)&Asd[wid * 32 + rt * 16 + lr][lg * 8];
#pragma unroll
        for (int ct = 0; ct < 4; ++ct)
            bf[ct] = *(const short8*)&Wtg[(size_t)(ct * 16 + lr) * WLD + k0 + lg * 8];
#pragma unroll
        for (int rt = 0; rt < 2; ++rt)
#pragma unroll
            for (int ct = 0; ct < 4; ++ct)
                acc[rt][ct] = __builtin_amdgcn_mfma_f32_16x16x32_bf16(af[rt], bf[ct], acc[rt][ct], 0, 0, 0);
        __syncthreads();
    }
#pragma unroll
    for (int rt = 0; rt < 2; ++rt)
#pragma unroll
        for (int q = 0; q < 4; ++q) {
            int gr = row0 + wid * 32 + rt * 16 + lg * 4 + q;
            if (gr < n) {
#pragma unroll
                for (int ct = 0; ct < 4; ++ct)
                    h1b[(size_t)gr * HOUT + ct * 16 + lr] = f2b(acc[rt][ct][q]);
            }
        }
}

__device__ void passA_body(int bid, const int* __restrict__ ei, int* __restrict__ gcur,
                           int* __restrict__ bkt, int E, int Etot, int nbuck,
                           int* hist, int* lbase) {
    int t = threadIdx.x;
    int base_e = bid * (256 * EPT);
    for (int j = t; j < 512; j += 256) hist[j] = 0;
    __syncthreads();
    for (int j = 0; j < EPT; ++j) {
        int idx = base_e + j * 256 + t;
        if (idx < Etot) {
            int d = (idx < E) ? ei[E + idx] : (idx - E);
            atomicAdd(&hist[d >> 8], 1);
        }
    }
    __syncthreads();
    for (int j = t; j < nbuck; j += 256) {
        int c = hist[j];
        lbase[j] = c ? atomicAdd(&gcur[j], c) : 0;
    }
    __syncthreads();
    for (int j = t; j < 512; j += 256) hist[j] = 0;
    __syncthreads();
    for (int j = 0; j < EPT; ++j) {
        int idx = base_e + j * 256 + t;
        if (idx < Etot) {
            int s, d;
            if (idx < E) { s = ei[idx]; d = ei[E + idx]; } else { s = idx - E; d = idx - E; }
            int b = d >> 8;
            int slot = atomicAdd(&hist[b], 1);
            bkt[lbase[b] + slot] = (s << 8) | (d & 255);   // packed 4B
        }
    }
}

__global__ __launch_bounds__(256) void work1_k(const float* __restrict__ x, const ushort* __restrict__ Wtg,
                                               ushort* __restrict__ h1b, int n,
                                               const int* __restrict__ ei, int* __restrict__ gcur,
                                               int* __restrict__ bkt, int E, int Etot, int nbuck, int g1) {
    __shared__ ushort Asd[128][40];
    __shared__ int hist[512];
    __shared__ int lbase[512];
    if ((int)blockIdx.x < g1) gemm1_body(blockIdx.x, x, Wtg, h1b, n, Asd);
    else passA_body(blockIdx.x - g1, ei, gcur, bkt, E, Etot, nbuck, hist, lbase);
}

// ---------------- bscan ----------------

__global__ __launch_bounds__(512) void bscan_k(const int* __restrict__ gcur, int* __restrict__ bbase,
                                               int* __restrict__ rowptr, int nbuck, int n, int Etot) {
    __shared__ int wsum[8];
    int t = threadIdx.x;
    int v = (t < nbuck) ? gcur[t] - t * CAP : 0;
    int lane = t & 63, w = t >> 6;
    int ss = v;
#pragma unroll
    for (int off = 1; off < 64; off <<= 1) { int t2 = __shfl_up(ss, off); if (lane >= off) ss += t2; }
    if (lane == 63) wsum[w] = ss;
    __syncthreads();
    int woff = 0;
    for (int j = 0; j < w; ++j) woff += wsum[j];
    if (t < nbuck) bbase[t] = woff + ss - v;
    if (t == 0) rowptr[n] = Etot;
}

// ---------------- work2: passB ∥ att1 (block-fused) ----------------

__device__ void passB_body(int b, const int* __restrict__ bkt, const int* __restrict__ gcur,
                           const int* __restrict__ bbase, int* __restrict__ rowptr,
                           int* __restrict__ col, int n, int* hist, int* lcur, int* wsum) {
    int t = threadIdx.x;
    int cnt = gcur[b] - b * CAP;
    int base = bbase[b];
    int d0 = b * DPB;
    int ndst = min(DPB, n - d0);
    const int* src = bkt + (size_t)b * CAP;
    hist[t] = 0;
    __syncthreads();
    for (int e = t; e < cnt; e += 256) {
        atomicAdd(&hist[src[e] & 255], 1);
    }
    __syncthreads();
    int v = hist[t];
    int lane = t & 63, w = t >> 6;
    int ss = v;
#pragma unroll
    for (int off = 1; off < 64; off <<= 1) { int t2 = __shfl_up(ss, off); if (lane >= off) ss += t2; }
    if (lane == 63) wsum[w] = ss;
    __syncthreads();
    int woff = 0;
    for (int j = 0; j < w; ++j) woff += wsum[j];
    int excl = woff + ss - v;
    if (t < ndst) rowptr[d0 + t] = base + excl;
    lcur[t] = excl;
    __syncthreads();
    for (int e = t; e < cnt; e += 256) {
        int u = src[e];
        int pos = atomicAdd(&lcur[u & 255], 1);
        col[base + pos] = (int)((unsigned)u >> 8);
    }
}

__device__ void att1_body(int bid, const ushort* __restrict__ h1b, const float* __restrict__ asw,
                          const float* __restrict__ adw, float* __restrict__ as1,
                          float* __restrict__ ad1, int n) {
    int t = bid * 256 + threadIdx.x;
    if (t >= n * HEADS) return;
    int hd = t & 7;
    const ushort* hp = h1b + (size_t)(t >> 3) * HOUT + hd * C1;
    short8 hv = *(const short8*)hp;
    float4 a0 = *(const float4*)(asw + hd * C1), a1 = *(const float4*)(asw + hd * C1 + 4);
    float4 d0 = *(const float4*)(adw + hd * C1), d1 = *(const float4*)(adw + hd * C1 + 4);
    float h0 = b2f((ushort)hv[0]), h1 = b2f((ushort)hv[1]), h2 = b2f((ushort)hv[2]), h3 = b2f((ushort)hv[3]);
    float h4 = b2f((ushort)hv[4]), h5 = b2f((ushort)hv[5]), h6 = b2f((ushort)hv[6]), h7 = b2f((ushort)hv[7]);
    as1[t] = h0*a0.x + h1*a0.y + h2*a0.z + h3*a0.w + h4*a1.x + h5*a1.y + h6*a1.z + h7*a1.w;
    ad1[t] = h0*d0.x + h1*d0.y + h2*d0.z + h3*d0.w + h4*d1.x + h5*d1.y + h6*d1.z + h7*d1.w;
}

__global__ __launch_bounds__(256) void work2_k(const int* __restrict__ bkt, const int* __restrict__ gcur,
                                               const int* __restrict__ bbase, int* __restrict__ rowptr,
                                               int* __restrict__ col, int n,
                                               const ushort* __restrict__ h1b, const float* __restrict__ asw,
                                               const float* __restrict__ adw, float* __restrict__ as1,
                                               float* __restrict__ ad1, int gpb) {
    __shared__ int hist[DPB];
    __shared__ int lcur[DPB];
    __shared__ int wsum[4];
    if ((int)blockIdx.x < gpb) passB_body(blockIdx.x, bkt, gcur, bbase, rowptr, col, n, hist, lcur, wsum);
    else att1_body(blockIdx.x - gpb, h1b, asw, adw, as1, ad1, n);
}

// ---------------- layer-1 aggregation: 2 nodes/wave, edge-pair gather ----------------
// Phase 3: lanes sl<16 -> even edges, sl>=16 -> odd edges, 4 ch (8B) per lane.
// Combine partials with shfl_xor(16); lanes sl<16 store ushort4 (8B).

__global__ __launch_bounds__(256) void l1agg_k(const ushort* __restrict__ h1b, const float* __restrict__ as1,
                                               const float* __restrict__ ad1, const float* __restrict__ b1,
                                               const int* __restrict__ rowptr, const int* __restrict__ col,
                                               ushort* __restrict__ hactb, int n) {
    __shared__ int2 pk_all[4][2 * 273];
    int wid = threadIdx.x >> 6, lane = threadIdx.x & 63;
    int nA = (blockIdx.x * 4 + wid) * 2;
    if (nA >= n) return;
    int nB = nA + 1;
    int na = lane >> 5, sl = lane & 31;
    int node = nA + na;
    bool nodev = node < n;
    int r0 = rowptr[nA];
    int r1 = rowptr[nA + 1];
    int r2 = (nB < n) ? rowptr[nB + 1] : r1;
    int degA = r1 - r0, degB = r2 - r1;
    int st  = na ? r1 : r0;
    int deg = na ? degB : degA;
    int2* pk = pk_all[wid];

    if (degA <= 32 && degB <= 32) {
        bool v = nodev && (sl < deg);
        int s = 0;
        float4 a0 = make_float4(0.f, 0.f, 0.f, 0.f), a1 = a0;
        if (v) {
            s = col[st + sl];
            a0 = *(const float4*)&as1[s * 8];
            a1 = *(const float4*)&as1[s * 8 + 4];
        }
        float4 d0 = make_float4(0.f, 0.f, 0.f, 0.f), d1 = d0;
        if (nodev) {
            d0 = *(const float4*)&ad1[node * 8];
            d1 = *(const float4*)&ad1[node * 8 + 4];
        }
        float ea[8] = {a0.x + d0.x, a0.y + d0.y, a0.z + d0.z, a0.w + d0.w,
                       a1.x + d1.x, a1.y + d1.y, a1.z + d1.z, a1.w + d1.w};
#pragma unroll
        for (int h = 0; h < 8; ++h) {
            float e0 = ea[h];
            float ee = v ? (e0 >= 0.f ? e0 : NEG * e0) : -1e30f;
            pk[na * 273 + h * 34 + sl] = make_int2(__float_as_int(ee), s);
        }
        __asm__ volatile("s_waitcnt lgkmcnt(0)" ::: "memory");
        __builtin_amdgcn_sched_barrier(0);
        {
            int t = lane & 3, h = (lane >> 2) & 7, na2 = lane >> 5;
            int base = na2 * 273 + h * 34;
            float e[8];
#pragma unroll
            for (int u = 0; u < 8; ++u) e[u] = __int_as_float(pk[base + t + 4 * u].x);
            float mx = e[0];
#pragma unroll
            for (int u = 1; u < 8; ++u) mx = fmaxf(mx, e[u]);
            mx = fmaxf(mx, __shfl_xor(mx, 1));
            mx = fmaxf(mx, __shfl_xor(mx, 2));
            float p[8], sm = 0.f;
#pragma unroll
            for (int u = 0; u < 8; ++u) { p[u] = __expf(e[u] - mx); sm += p[u]; }
            sm += __shfl_xor(sm, 1);
            sm += __shfl_xor(sm, 2);
            float inv = 1.f / (sm + 1e-16f);
#pragma unroll
            for (int u = 0; u < 8; ++u) pk[base + t + 4 * u].x = __float_as_int(p[u] * inv);
        }
        __asm__ volatile("s_waitcnt lgkmcnt(0)" ::: "memory");
        __builtin_amdgcn_sched_barrier(0);
        // phase 3: edge-pair gather. cl = channel-lane (4 ch), eo = edge parity.
        int cl = sl & 15;
        int eo = sl >> 4;
        int pb = na * 273 + (cl >> 1) * 34 + eo;
        float acc0 = 0.f, acc1 = 0.f, acc2 = 0.f, acc3 = 0.f;
        int mdeg = max(degA, degB);
#pragma unroll 2
        for (int g = 0; 2 * g < mdeg; ++g) {
            int2 p2 = pk[pb + 2 * g];
            float w = __int_as_float(p2.x);
            uint2 hv = *(const uint2*)&h1b[(size_t)p2.y * HOUT + 4 * cl];
            acc0 += w * b2f_lo(hv.x);
            acc1 += w * b2f_hi(hv.x);
            acc2 += w * b2f_lo(hv.y);
            acc3 += w * b2f_hi(hv.y);
        }
        acc0 += __shfl_xor(acc0, 16);
        acc1 += __shfl_xor(acc1, 16);
        acc2 += __shfl_xor(acc2, 16);
        acc3 += __shfl_xor(acc3, 16);
        if (nodev && eo == 0) {
            float4 bb = *(const float4*)&b1[4 * cl];
            float o0 = acc0 + bb.x, o1 = acc1 + bb.y, o2 = acc2 + bb.z, o3 = acc3 + bb.w;
            float e0 = o0 > 0.f ? o0 : expm1f(o0);
            float e1 = o1 > 0.f ? o1 : expm1f(o1);
            float e2 = o2 > 0.f ? o2 : expm1f(o2);
            float e3 = o3 > 0.f ? o3 : expm1f(o3);
            ushort4 op = make_ushort4(f2b(e0), f2b(e1), f2b(e2), f2b(e3));
            *(ushort4*)&hactb[(size_t)node * HOUT + 4 * cl] = op;
        }
    } else {
        // rare fallback: serial online softmax per half, 2 channels per lane (own layout)
        int hd = sl >> 2;
        float ad = nodev ? ad1[node * 8 + hd] : 0.f;
        float m = -1e30f, den = 0.f, a0 = 0.f, a1 = 0.f;
        int en = st + deg;
        for (int e = st; e < en; ++e) {
            int s = col[e];
            float e0 = as1[s * 8 + hd] + ad;
            float ee = e0 >= 0.f ? e0 : NEG * e0;
            unsigned hv = *(const unsigned*)&h1b[(size_t)s * HOUT + 2 * sl];
            float mn = fmaxf(m, ee);
            float sc = __expf(m - mn), p = __expf(ee - mn);
            den = den * sc + p;
            a0 = a0 * sc + p * b2f_lo(hv);
            a1 = a1 * sc + p * b2f_hi(hv);
            m = mn;
        }
        float2 bb = *(const float2*)&b1[2 * sl];
        float o0 = a0 / (den + 1e-16f) + bb.x;
        float o1 = a1 / (den + 1e-16f) + bb.y;
        float e0 = o0 > 0.f ? o0 : expm1f(o0);
        float e1 = o1 > 0.f ? o1 : expm1f(o1);
        unsigned op = (unsigned)f2b(e0) | ((unsigned)f2b(e1) << 16);
        if (nodev) *(unsigned*)&hactb[(size_t)node * HOUT + 2 * sl] = op;
    }
}

// ---------------- layer-2 GEMM (64->40) + attention dots: MFMA, no LDS ----------------

__global__ __launch_bounds__(256) void g2_k(const ushort* __restrict__ hactb, const ushort* __restrict__ W2t,
                                            const float* __restrict__ asw, const float* __restrict__ adw,
                                            ushort* __restrict__ h2b, float* __restrict__ as2,
                                            float* __restrict__ ad2, int n) {
    int tid = threadIdx.x;
    int lane = tid & 63, wid = tid >> 6;
    int lr = lane & 15, lg = lane >> 4;
    int row0 = blockIdx.x * 64 + wid * 16;
    if (row0 >= n) return;
    int gr = row0 + lr;
    bool vr = gr < n;
    f32x4 acc[3];
#pragma unroll
    for (int ct = 0; ct < 3; ++ct) acc[ct] = (f32x4){0.f, 0.f, 0.f, 0.f};
    const short8 z8 = (short8){0, 0, 0, 0, 0, 0, 0, 0};
#pragma unroll
    for (int ks = 0; ks < 2; ++ks) {
        short8 af = vr ? *(const short8*)&hactb[(size_t)gr * HOUT + ks * 32 + lg * 8] : z8;
#pragma unroll
        for (int ct = 0; ct < 3; ++ct) {
            short8 bf = *(const short8*)&W2t[(ct * 16 + lr) * HOUT + ks * 32 + lg * 8];
            acc[ct] = __builtin_amdgcn_mfma_f32_16x16x32_bf16(af, bf, acc[ct], 0, 0, 0);
        }
    }
    float av4[4], dv4[4];
#pragma unroll
    for (int q = 0; q < 4; ++q) {
        int r = row0 + lg * 4 + q;
        bool vw = r < n;
        float av = 0.f, dv = 0.f;
#pragma unroll
        for (int ct = 0; ct < 3; ++ct) {
            int c = ct * 16 + lr;
            if (c < NCLS) {
                float o = acc[ct][q];
                av += o * asw[c];
                dv += o * adw[c];
                if (vw) h2b[(size_t)r * NCLS + c] = f2b(o);
            }
        }
        av += __shfl_xor(av, 1); av += __shfl_xor(av, 2); av += __shfl_xor(av, 4); av += __shfl_xor(av, 8);
        dv += __shfl_xor(dv, 1); dv += __shfl_xor(dv, 2); dv += __shfl_xor(dv, 4); dv += __shfl_xor(dv, 8);
        av4[q] = av; dv4[q] = dv;
    }
#pragma unroll
    for (int q = 0; q < 4; ++q) {
        int r = row0 + lg * 4 + q;
        if (lr == q && r < n) as2[r] = av4[q];
        if (lr == 8 + q && r < n) ad2[r] = dv4[q];
    }
}

// ---------------- layer-2 aggregation + log_softmax: 2 nodes/wave, edge-pair gather ----------------
// Gather lanes: sl<10 -> even edges, sl in [10,20) -> odd edges, 4 ch (8B) each.
// Combine via shfl(lane+10); log_softmax in 10-lane x 4ch layout (neutral lanes 10-15).

__global__ __launch_bounds__(256) void l2agg_k(const ushort* __restrict__ h2b, const float* __restrict__ as2,
                                               const float* __restrict__ ad2, const float* __restrict__ b2,
                                               const int* __restrict__ rowptr, const int* __restrict__ col,
                                               float* __restrict__ out, int n) {
    __shared__ int2 pk_all[4][2 * 40];
    int wid = threadIdx.x >> 6, lane = threadIdx.x & 63;
    int nA = (blockIdx.x * 4 + wid) * 2;
    if (nA >= n) return;
    int nB = nA + 1;
    int na = lane >> 5, sl = lane & 31;
    int node = nA + na;
    bool nodev = node < n;
    int r0 = rowptr[nA];
    int r1 = rowptr[nA + 1];
    int r2 = (nB < n) ? rowptr[nB + 1] : r1;
    int degA = r1 - r0, degB = r2 - r1;
    int st  = na ? r1 : r0;
    int deg = na ? degB : degA;

    if (degA <= 32 && degB <= 32) {
        int2* pk = pk_all[wid];
        bool v = nodev && (sl < deg);
        int s = 0; float av = 0.f;
        if (v) { s = col[st + sl]; av = as2[s]; }
        float ad = nodev ? ad2[node] : 0.f;
        float ev = av + ad;
        float ee = v ? (ev >= 0.f ? ev : NEG * ev) : -1e30f;
        float m = ee;
        m = fmaxf(m, __shfl_xor(m, 1)); m = fmaxf(m, __shfl_xor(m, 2));
        m = fmaxf(m, __shfl_xor(m, 4)); m = fmaxf(m, __shfl_xor(m, 8));
        m = fmaxf(m, __shfl_xor(m, 16));
        float p = __expf(ee - m);
        float d = p;
        d += __shfl_xor(d, 1); d += __shfl_xor(d, 2); d += __shfl_xor(d, 4);
        d += __shfl_xor(d, 8); d += __shfl_xor(d, 16);
        float w = p / (d + 1e-16f);
        pk[na * 40 + sl] = make_int2(__float_as_int(w), s);
        __asm__ volatile("s_waitcnt lgkmcnt(0)" ::: "memory");
        __builtin_amdgcn_sched_barrier(0);
        // edge-pair gather
        bool gact = sl < 20;
        int cl = sl % 10;            // channel-lane: ch 4*cl .. 4*cl+3
        int eo = sl / 10;            // 0: even edges, 1: odd (only gact lanes meaningful)
        float acc0 = 0.f, acc1 = 0.f, acc2 = 0.f, acc3 = 0.f;
        int mdeg = max(degA, degB);
#pragma unroll 2
        for (int g = 0; 2 * g < mdeg; ++g) {
            int j = gact ? (2 * g + eo) : 0;
            int2 p2 = pk[na * 40 + j];
            float wv = __int_as_float(p2.x);
            if (gact) {
                uint2 hv = *(const uint2*)&h2b[(size_t)p2.y * NCLS + 4 * cl];
                acc0 += wv * b2f_lo(hv.x);
                acc1 += wv * b2f_hi(hv.x);
                acc2 += wv * b2f_lo(hv.y);
                acc3 += wv * b2f_hi(hv.y);
            }
        }
        // combine even/odd partials: lane sl<10 += lane sl+10
        int self = threadIdx.x & 63;
        float p0 = __shfl(acc0, self + 10);
        float p1 = __shfl(acc1, self + 10);
        float p2s = __shfl(acc2, self + 10);
        float p3 = __shfl(acc3, self + 10);
        bool fin = sl < 10;
        float z0, z1, z2, z3;
        if (fin) {
            float4 bb = *(const float4*)&b2[4 * cl];
            z0 = acc0 + p0 + bb.x; z1 = acc1 + p1 + bb.y;
            z2 = acc2 + p2s + bb.z; z3 = acc3 + p3 + bb.w;
        } else { z0 = z1 = z2 = z3 = -1e30f; }
        float zm = fin ? fmaxf(fmaxf(z0, z1), fmaxf(z2, z3)) : -1e30f;
        zm = fmaxf(zm, __shfl_xor(zm, 1)); zm = fmaxf(zm, __shfl_xor(zm, 2));
        zm = fmaxf(zm, __shfl_xor(zm, 4)); zm = fmaxf(zm, __shfl_xor(zm, 8));
        float ex = fin ? (__expf(z0 - zm) + __expf(z1 - zm) + __expf(z2 - zm) + __expf(z3 - zm)) : 0.f;
        ex += __shfl_xor(ex, 1); ex += __shfl_xor(ex, 2);
        ex += __shfl_xor(ex, 4); ex += __shfl_xor(ex, 8);
        float ls = logf(ex);
        if (fin && nodev) {
            float4 o = make_float4(z0 - zm - ls, z1 - zm - ls, z2 - zm - ls, z3 - zm - ls);
            *(float4*)&out[(size_t)node * NCLS + 4 * cl] = o;
        }
    } else {
        // rare fallback: serial online softmax per half, 20 lanes x 2ch (own tail)
        bool act = sl < 20;
        float z0, z1;
        float ad = nodev ? ad2[node] : 0.f;
        float m = -1e30f, den = 0.f, a0 = 0.f, a1 = 0.f;
        int en = st + deg;
        for (int e = st; e < en; ++e) {
            int s = col[e];
            float ev = as2[s] + ad;
            float ee = ev >= 0.f ? ev : NEG * ev;
            float mn = fmaxf(m, ee);
            float sc = __expf(m - mn), p = __expf(ee - mn);
            den = den * sc + p;
            if (act) {
                unsigned hv = *(const unsigned*)&h2b[(size_t)s * NCLS + 2 * sl];
                a0 = a0 * sc + p * b2f_lo(hv);
                a1 = a1 * sc + p * b2f_hi(hv);
            }
            m = mn;
        }
        if (act) {
            float2 bb = *(const float2*)&b2[2 * sl];
            z0 = a0 / (den + 1e-16f) + bb.x;
            z1 = a1 / (den + 1e-16f) + bb.y;
        } else { z0 = z1 = -1e30f; }
        float zm = fmaxf(z0, z1);
        zm = fmaxf(zm, __shfl_xor(zm, 1)); zm = fmaxf(zm, __shfl_xor(zm, 2));
        zm = fmaxf(zm, __shfl_xor(zm, 4)); zm = fmaxf(zm, __shfl_xor(zm, 8));
        zm = fmaxf(zm, __shfl_xor(zm, 16));
        float ex = act ? (__expf(z0 - zm) + __expf(z1 - zm)) : 0.f;
        ex += __shfl_xor(ex, 1); ex += __shfl_xor(ex, 2); ex += __shfl_xor(ex, 4);
        ex += __shfl_xor(ex, 8); ex += __shfl_xor(ex, 16);
        float ls = logf(ex);
        if (act && nodev) {
            float2 o = make_float2(z0 - zm - ls, z1 - zm - ls);
            *(float2*)&out[(size_t)node * NCLS + 2 * sl] = o;
        }
    }
}

// ---------------- host ----------------

extern "C" void kernel_launch(void* const* d_in, const int* in_sizes, int n_in,
                              void* d_out, int out_size, void* d_ws, size_t ws_size,
                              hipStream_t stream) {
    const float* x    = (const float*)d_in[0];
    const int*   ei   = (const int*)d_in[1];
    const float* W1   = (const float*)d_in[2];
    const float* asw1 = (const float*)d_in[3];
    const float* adw1 = (const float*)d_in[4];
    const float* b1   = (const float*)d_in[5];
    const float* W2   = (const float*)d_in[6];
    const float* asw2 = (const float*)d_in[7];
    const float* adw2 = (const float*)d_in[8];
    const float* b2   = (const float*)d_in[9];
    float* out = (float*)d_out;

    const int n = in_sizes[0] / F_IN;          // 100000
    const int E = in_sizes[1] / 2;             // 1600000
    const int Etot = E + n;
    const int nbuck = (n + DPB - 1) / DPB;     // 391
    const int npair = (n + 1) / 2;

    char* ws = (char*)d_ws;
    size_t off = 0;
    auto alloc = [&](size_t bytes) -> void* {
        void* p = ws + off;
        off = (off + bytes + 255) & ~(size_t)255;
        return p;
    };
    int*    gcur   = (int*)alloc((size_t)nbuck * 4);
    int*    bbase  = (int*)alloc((size_t)nbuck * 4);
    int*    rowptr = (int*)alloc((size_t)(n + 1) * 4);
    int*    col    = (int*)alloc((size_t)Etot * 4);
    int*    bkt    = (int*)alloc((size_t)nbuck * CAP * 4);           // 12.6 MB (packed 4B)
    ushort* h1b    = (ushort*)alloc((size_t)n * HOUT * 2);           // 12.8 MB (reused as h2b)
    float*  as1    = (float*)alloc((size_t)n * HEADS * 4);
    float*  ad1    = (float*)alloc((size_t)n * HEADS * 4);
    ushort* hactb  = (ushort*)alloc((size_t)n * HOUT * 2);           // 12.8 MB
    ushort* Wtg    = (ushort*)alloc((size_t)HOUT * WLD * 2);
    ushort* W2t    = (ushort*)alloc((size_t)48 * HOUT * 2);
    ushort* h2b = h1b;   // h1b dead after l1agg
    float*  as2 = (float*)(h1b + (size_t)n * NCLS);
    float*  ad2 = as2 + n;

    const int g1 = (n + 127) / 128;                       // gemm1 blocks
    const int gpa = (Etot + 256 * EPT - 1) / (256 * EPT); // passA blocks
    const int gpb = nbuck;                                // passB blocks
    const int gat = (n * HEADS + 255) / 256;              // att1 blocks

    prep_k<<<142, 256, 0, stream>>>(W1, W2, gcur, Wtg, W2t, nbuck);
    work1_k<<<g1 + gpa, 256, 0, stream>>>(x, Wtg, h1b, n, ei, gcur, bkt, E, Etot, nbuck, g1);
    bscan_k<<<1, 512, 0, stream>>>(gcur, bbase, rowptr, nbuck, n, Etot);
    work2_k<<<gpb + gat, 256, 0, stream>>>(bkt, gcur, bbase, rowptr, col, n,
                                           h1b, asw1, adw1, as1, ad1, gpb);
    l1agg_k<<<(npair + 3) / 4, 256, 0, stream>>>(h1b, as1, ad1, b1, rowptr, col, hactb, n);
    g2_k<<<(n + 63) / 64, 256, 0, stream>>>(hactb, W2t, asw2, adw2, h2b, as2, ad2, n);
    l2agg_k<<<(npair + 3) / 4, 256, 0, stream>>>(h2b, as2, ad2, b2, rowptr, col, out, n);
}

// Round 11
// 218.099 us; speedup vs baseline: 1.3372x; 1.0715x over previous
//
#include <hip/hip_runtime.h>
#include <hip/hip_bf16.h>
#include <math.h>

#define F_IN 512
#define HOUT 64      // HEADS*C1
#define HEADS 8
#define C1 8
#define NCLS 40
#define NEG 0.2f

#define DPB 256            // dsts per bucket
#define CAP 8064           // staging + col capacity per bucket
#define EPT 32             // edges per thread in passA
#define WLD 520            // padded K-stride of transposed bf16 W1

typedef __attribute__((ext_vector_type(8))) short short8;
typedef __attribute__((ext_vector_type(4))) float f32x4;

__device__ __forceinline__ ushort f2b(float f) {
    union { float f; unsigned u; } v; v.f = f;
    unsigned r = (v.u + 0x7FFFu + ((v.u >> 16) & 1u)) >> 16;   // RNE
    return (ushort)r;
}
__device__ __forceinline__ float b2f(ushort b) {
    union { unsigned u; float f; } v; v.u = ((unsigned)b) << 16;
    return v.f;
}
__device__ __forceinline__ float b2f_lo(unsigned u) { union { unsigned u; float f; } v; v.u = u << 16; return v.f; }
__device__ __forceinline__ float b2f_hi(unsigned u) { union { unsigned u; float f; } v; v.u = u & 0xFFFF0000u; return v.f; }

// ---------------- prep: init ∥ wconv ∥ w2conv (block-fused) ----------------

__global__ __launch_bounds__(256) void prep_k(const float* __restrict__ W1, const float* __restrict__ W2,
                                              int* __restrict__ gcur, ushort* __restrict__ Wtg,
                                              ushort* __restrict__ W2t, int nbuck) {
    int bid = blockIdx.x, t = threadIdx.x;
    if (bid < 128) {                       // wconv: W1 -> Wtg[c][k] bf16, padded
        int idx = bid * 256 + t;
        int k = idx >> 6, c = idx & 63;
        Wtg[(size_t)c * WLD + k] = f2b(W1[idx]);
    } else if (bid < 140) {                // w2conv: W2 -> W2t[48][64] (cols>=40 zero)
        int idx = (bid - 128) * 256 + t;
        int c = idx >> 6, k = idx & 63;
        W2t[idx] = (c < NCLS) ? f2b(W2[k * NCLS + c]) : 0;
    } else {                               // init gcur
        int b = (bid - 140) * 256 + t;
        if (b < nbuck) gcur[b] = b * CAP;
    }
}

// ---------------- work1: gemm1 ∥ passA (block-fused) ----------------

__device__ void gemm1_body(int bid, const float* __restrict__ x, const ushort* __restrict__ Wtg,
                           ushort* __restrict__ h1b, int n, ushort Asd[128][40]) {
    int tid = threadIdx.x;
    int lane = tid & 63, wid = tid >> 6;
    int lr = lane & 15, lg = lane >> 4;
    int row0 = bid * 128;
    f32x4 acc[2][4];
#pragma unroll
    for (int rt = 0; rt < 2; ++rt)
#pragma unroll
        for (int ct = 0; ct < 4; ++ct) acc[rt][ct] = (f32x4){0.f, 0.f, 0.f, 0.f};

    for (int k0 = 0; k0 < F_IN; k0 += 32) {
#pragma unroll
        for (int j = 0; j < 4; ++j) {
            int idx = tid + j * 256;
            int r = idx >> 3;
            int k4 = (idx & 7) << 2;
            int gr = row0 + r;
            float4 v = (gr < n) ? *(const float4*)&x[(size_t)gr * F_IN + k0 + k4]
                                : make_float4(0.f, 0.f, 0.f, 0.f);
            ushort4 b4 = make_ushort4(f2b(v.x), f2b(v.y), f2b(v.z), f2b(v.w));
            *(ushort4*)&Asd[r][k4] = b4;
        }
        __syncthreads();
        short8 af[2], bf[4];
#pragma unroll
        for (int rt = 0; rt < 2; ++rt)
            af[rt] = *(const short8*)&Asd[wid * 32 + rt * 16 + lr][lg * 8];
#pragma unroll
        for (int ct = 0; ct < 4; ++ct)
            bf[ct] = *(const short8*)&Wtg[(size_t)(ct * 16 + lr) * WLD + k0 + lg * 8];
#pragma unroll
        for (int rt = 0; rt < 2; ++rt)
#pragma unroll
            for (int ct = 0; ct < 4; ++ct)
                acc[rt][ct] = __builtin_amdgcn_mfma_f32_16x16x32_bf16(af[rt], bf[ct], acc[rt][ct], 0, 0, 0);
        __syncthreads();
    }
#pragma unroll
    for (int rt = 0; rt < 2; ++rt)
#pragma unroll
        for (int q = 0; q < 4; ++q) {
            int gr = row0 + wid * 32 + rt * 16 + lg * 4 + q;
            if (gr < n) {
#pragma unroll
                for (int ct = 0; ct < 4; ++ct)
                    h1b[(size_t)gr * HOUT + ct * 16 + lr] = f2b(acc[rt][ct][q]);
            }
        }
}

__device__ void passA_body(int bid, const int* __restrict__ ei, int* __restrict__ gcur,
                           int* __restrict__ bkt, int E, int Etot, int nbuck,
                           int* hist, int* lbase) {
    int t = threadIdx.x;
    int base_e = bid * (256 * EPT);
    for (int j = t; j < 512; j += 256) hist[j] = 0;
    __syncthreads();
    for (int j = 0; j < EPT; ++j) {
        int idx = base_e + j * 256 + t;
        if (idx < Etot) {
            int d = (idx < E) ? ei[E + idx] : (idx - E);
            atomicAdd(&hist[d >> 8], 1);
        }
    }
    __syncthreads();
    for (int j = t; j < nbuck; j += 256) {
        int c = hist[j];
        lbase[j] = c ? atomicAdd(&gcur[j], c) : 0;
    }
    __syncthreads();
    for (int j = t; j < 512; j += 256) hist[j] = 0;
    __syncthreads();
    for (int j = 0; j < EPT; ++j) {
        int idx = base_e + j * 256 + t;
        if (idx < Etot) {
            int s, d;
            if (idx < E) { s = ei[idx]; d = ei[E + idx]; } else { s = idx - E; d = idx - E; }
            int b = d >> 8;
            int slot = atomicAdd(&hist[b], 1);
            bkt[lbase[b] + slot] = (s << 8) | (d & 255);   // packed 4B
        }
    }
}

__global__ __launch_bounds__(256) void work1_k(const float* __restrict__ x, const ushort* __restrict__ Wtg,
                                               ushort* __restrict__ h1b, int n,
                                               const int* __restrict__ ei, int* __restrict__ gcur,
                                               int* __restrict__ bkt, int E, int Etot, int nbuck, int g1) {
    __shared__ ushort Asd[128][40];
    __shared__ int hist[512];
    __shared__ int lbase[512];
    if ((int)blockIdx.x < g1) gemm1_body(blockIdx.x, x, Wtg, h1b, n, Asd);
    else passA_body(blockIdx.x - g1, ei, gcur, bkt, E, Etot, nbuck, hist, lbase);
}

// ---------------- work2: passB ∥ att1 (block-fused); passB self-based, writes rowse ----------------

__device__ void passB_body(int b, const int* __restrict__ bkt, const int* __restrict__ gcur,
                           int2* __restrict__ rowse, int* __restrict__ col, int n,
                           int* hist, int* lcur, int* wsum) {
    int t = threadIdx.x;
    int cnt = gcur[b] - b * CAP;
    int base = b * CAP;                  // fixed per-bucket col base (col padded per bucket)
    int d0 = b * DPB;
    int ndst = min(DPB, n - d0);
    const int* src = bkt + (size_t)b * CAP;
    hist[t] = 0;
    __syncthreads();
    for (int e = t; e < cnt; e += 256) {
        atomicAdd(&hist[src[e] & 255], 1);
    }
    __syncthreads();
    int v = hist[t];
    int lane = t & 63, w = t >> 6;
    int ss = v;
#pragma unroll
    for (int off = 1; off < 64; off <<= 1) { int t2 = __shfl_up(ss, off); if (lane >= off) ss += t2; }
    if (lane == 63) wsum[w] = ss;
    __syncthreads();
    int woff = 0;
    for (int j = 0; j < w; ++j) woff += wsum[j];
    int excl = woff + ss - v;
    if (t < ndst) rowse[d0 + t] = make_int2(base + excl, base + excl + v);
    lcur[t] = excl;
    __syncthreads();
    for (int e = t; e < cnt; e += 256) {
        int u = src[e];
        int pos = atomicAdd(&lcur[u & 255], 1);
        col[base + pos] = (int)((unsigned)u >> 8);
    }
}

__device__ void att1_body(int bid, const ushort* __restrict__ h1b, const float* __restrict__ asw,
                          const float* __restrict__ adw, float* __restrict__ as1,
                          float* __restrict__ ad1, int n) {
    int t = bid * 256 + threadIdx.x;
    if (t >= n * HEADS) return;
    int hd = t & 7;
    const ushort* hp = h1b + (size_t)(t >> 3) * HOUT + hd * C1;
    short8 hv = *(const short8*)hp;
    float4 a0 = *(const float4*)(asw + hd * C1), a1 = *(const float4*)(asw + hd * C1 + 4);
    float4 d0 = *(const float4*)(adw + hd * C1), d1 = *(const float4*)(adw + hd * C1 + 4);
    float h0 = b2f((ushort)hv[0]), h1 = b2f((ushort)hv[1]), h2 = b2f((ushort)hv[2]), h3 = b2f((ushort)hv[3]);
    float h4 = b2f((ushort)hv[4]), h5 = b2f((ushort)hv[5]), h6 = b2f((ushort)hv[6]), h7 = b2f((ushort)hv[7]);
    as1[t] = h0*a0.x + h1*a0.y + h2*a0.z + h3*a0.w + h4*a1.x + h5*a1.y + h6*a1.z + h7*a1.w;
    ad1[t] = h0*d0.x + h1*d0.y + h2*d0.z + h3*d0.w + h4*d1.x + h5*d1.y + h6*d1.z + h7*d1.w;
}

__global__ __launch_bounds__(256) void work2_k(const int* __restrict__ bkt, const int* __restrict__ gcur,
                                               int2* __restrict__ rowse, int* __restrict__ col, int n,
                                               const ushort* __restrict__ h1b, const float* __restrict__ asw,
                                               const float* __restrict__ adw, float* __restrict__ as1,
                                               float* __restrict__ ad1, int gpb) {
    __shared__ int hist[DPB];
    __shared__ int lcur[DPB];
    __shared__ int wsum[4];
    if ((int)blockIdx.x < gpb) passB_body(blockIdx.x, bkt, gcur, rowse, col, n, hist, lcur, wsum);
    else att1_body(blockIdx.x - gpb, h1b, asw, adw, as1, ad1, n);
}

// ---------------- layer-1 aggregation: 2 nodes/wave, edge-pair gather, batch-4 MLP ----------------

__global__ __launch_bounds__(256) void l1agg_k(const ushort* __restrict__ h1b, const float* __restrict__ as1,
                                               const float* __restrict__ ad1, const float* __restrict__ b1,
                                               const int2* __restrict__ rowse, const int* __restrict__ col,
                                               ushort* __restrict__ hactb, int n) {
    __shared__ int2 pk_all[4][2 * 273];
    int wid = threadIdx.x >> 6, lane = threadIdx.x & 63;
    int nA = (blockIdx.x * 4 + wid) * 2;
    if (nA >= n) return;
    int nB = nA + 1;
    int na = lane >> 5, sl = lane & 31;
    int node = nA + na;
    bool nodev = node < n;
    int4 rr = *(const int4*)&rowse[nA];           // (stA,enA,stB,enB); nA even -> 16B aligned
    if (nB >= n) { rr.z = rr.y; rr.w = rr.y; }    // degB = 0 (wave-uniform; n even in practice)
    int degA = rr.y - rr.x, degB = rr.w - rr.z;
    int st  = na ? rr.z : rr.x;
    int deg = na ? degB : degA;
    int2* pk = pk_all[wid];

    if (degA <= 32 && degB <= 32) {
        bool v = nodev && (sl < deg);
        int s = 0;
        float4 a0 = make_float4(0.f, 0.f, 0.f, 0.f), a1 = a0;
        if (v) {
            s = col[st + sl];
            a0 = *(const float4*)&as1[s * 8];
            a1 = *(const float4*)&as1[s * 8 + 4];
        }
        float4 d0 = make_float4(0.f, 0.f, 0.f, 0.f), d1 = d0;
        if (nodev) {
            d0 = *(const float4*)&ad1[node * 8];
            d1 = *(const float4*)&ad1[node * 8 + 4];
        }
        float ea[8] = {a0.x + d0.x, a0.y + d0.y, a0.z + d0.z, a0.w + d0.w,
                       a1.x + d1.x, a1.y + d1.y, a1.z + d1.z, a1.w + d1.w};
#pragma unroll
        for (int h = 0; h < 8; ++h) {
            float e0 = ea[h];
            float ee = v ? (e0 >= 0.f ? e0 : NEG * e0) : -1e30f;
            pk[na * 273 + h * 34 + sl] = make_int2(__float_as_int(ee), s);
        }
        __asm__ volatile("s_waitcnt lgkmcnt(0)" ::: "memory");
        __builtin_amdgcn_sched_barrier(0);
        {
            int t = lane & 3, h = (lane >> 2) & 7, na2 = lane >> 5;
            int base = na2 * 273 + h * 34;
            float e[8];
#pragma unroll
            for (int u = 0; u < 8; ++u) e[u] = __int_as_float(pk[base + t + 4 * u].x);
            float mx = e[0];
#pragma unroll
            for (int u = 1; u < 8; ++u) mx = fmaxf(mx, e[u]);
            mx = fmaxf(mx, __shfl_xor(mx, 1));
            mx = fmaxf(mx, __shfl_xor(mx, 2));
            float p[8], sm = 0.f;
#pragma unroll
            for (int u = 0; u < 8; ++u) { p[u] = __expf(e[u] - mx); sm += p[u]; }
            sm += __shfl_xor(sm, 1);
            sm += __shfl_xor(sm, 2);
            float inv = 1.f / (sm + 1e-16f);
#pragma unroll
            for (int u = 0; u < 8; ++u) pk[base + t + 4 * u].x = __float_as_int(p[u] * inv);
        }
        __asm__ volatile("s_waitcnt lgkmcnt(0)" ::: "memory");
        __builtin_amdgcn_sched_barrier(0);
        // phase 3: edge-pair gather, batch-4 (4 ds_reads then 4 gathers in flight)
        int cl = sl & 15;
        int eo = sl >> 4;
        int pb = na * 273 + (cl >> 1) * 34 + eo;
        float acc0 = 0.f, acc1 = 0.f, acc2 = 0.f, acc3 = 0.f;
        int mdeg = max(degA, degB);
        for (int g0 = 0; 2 * g0 < mdeg; g0 += 4) {
            int2 qa = pk[pb + 2 * g0];
            int2 qb = pk[pb + 2 * g0 + 2];
            int2 qc = pk[pb + 2 * g0 + 4];
            int2 qd = pk[pb + 2 * g0 + 6];        // max slot 31 < 34; out-of-deg slots carry w=0
            uint2 ha = *(const uint2*)&h1b[(size_t)qa.y * HOUT + 4 * cl];
            uint2 hb = *(const uint2*)&h1b[(size_t)qb.y * HOUT + 4 * cl];
            uint2 hc = *(const uint2*)&h1b[(size_t)qc.y * HOUT + 4 * cl];
            uint2 hd = *(const uint2*)&h1b[(size_t)qd.y * HOUT + 4 * cl];
            float wa = __int_as_float(qa.x), wb = __int_as_float(qb.x);
            float wc = __int_as_float(qc.x), wd = __int_as_float(qd.x);
            acc0 += wa * b2f_lo(ha.x) + wb * b2f_lo(hb.x) + wc * b2f_lo(hc.x) + wd * b2f_lo(hd.x);
            acc1 += wa * b2f_hi(ha.x) + wb * b2f_hi(hb.x) + wc * b2f_hi(hc.x) + wd * b2f_hi(hd.x);
            acc2 += wa * b2f_lo(ha.y) + wb * b2f_lo(hb.y) + wc * b2f_lo(hc.y) + wd * b2f_lo(hd.y);
            acc3 += wa * b2f_hi(ha.y) + wb * b2f_hi(hb.y) + wc * b2f_hi(hc.y) + wd * b2f_hi(hd.y);
        }
        acc0 += __shfl_xor(acc0, 16);
        acc1 += __shfl_xor(acc1, 16);
        acc2 += __shfl_xor(acc2, 16);
        acc3 += __shfl_xor(acc3, 16);
        if (nodev && eo == 0) {
            float4 bb = *(const float4*)&b1[4 * cl];
            float o0 = acc0 + bb.x, o1 = acc1 + bb.y, o2 = acc2 + bb.z, o3 = acc3 + bb.w;
            float e0 = o0 > 0.f ? o0 : expm1f(o0);
            float e1 = o1 > 0.f ? o1 : expm1f(o1);
            float e2 = o2 > 0.f ? o2 : expm1f(o2);
            float e3 = o3 > 0.f ? o3 : expm1f(o3);
            ushort4 op = make_ushort4(f2b(e0), f2b(e1), f2b(e2), f2b(e3));
            *(ushort4*)&hactb[(size_t)node * HOUT + 4 * cl] = op;
        }
    } else {
        // rare fallback: serial online softmax per half, 2 channels per lane (own layout)
        int hd = sl >> 2;
        float ad = nodev ? ad1[node * 8 + hd] : 0.f;
        float m = -1e30f, den = 0.f, a0 = 0.f, a1 = 0.f;
        int en = st + deg;
        for (int e = st; e < en; ++e) {
            int s = col[e];
            float e0 = as1[s * 8 + hd] + ad;
            float ee = e0 >= 0.f ? e0 : NEG * e0;
            unsigned hv = *(const unsigned*)&h1b[(size_t)s * HOUT + 2 * sl];
            float mn = fmaxf(m, ee);
            float sc = __expf(m - mn), p = __expf(ee - mn);
            den = den * sc + p;
            a0 = a0 * sc + p * b2f_lo(hv);
            a1 = a1 * sc + p * b2f_hi(hv);
            m = mn;
        }
        float2 bb = *(const float2*)&b1[2 * sl];
        float o0 = a0 / (den + 1e-16f) + bb.x;
        float o1 = a1 / (den + 1e-16f) + bb.y;
        float e0 = o0 > 0.f ? o0 : expm1f(o0);
        float e1 = o1 > 0.f ? o1 : expm1f(o1);
        unsigned op = (unsigned)f2b(e0) | ((unsigned)f2b(e1) << 16);
        if (nodev) *(unsigned*)&hactb[(size_t)node * HOUT + 2 * sl] = op;
    }
}

// ---------------- layer-2 GEMM (64->40) + attention dots: MFMA, no LDS ----------------

__global__ __launch_bounds__(256) void g2_k(const ushort* __restrict__ hactb, const ushort* __restrict__ W2t,
                                            const float* __restrict__ asw, const float* __restrict__ adw,
                                            ushort* __restrict__ h2b, float* __restrict__ as2,
                                            float* __restrict__ ad2, int n) {
    int tid = threadIdx.x;
    int lane = tid & 63, wid = tid >> 6;
    int lr = lane & 15, lg = lane >> 4;
    int row0 = blockIdx.x * 64 + wid * 16;
    if (row0 >= n) return;
    int gr = row0 + lr;
    bool vr = gr < n;
    f32x4 acc[3];
#pragma unroll
    for (int ct = 0; ct < 3; ++ct) acc[ct] = (f32x4){0.f, 0.f, 0.f, 0.f};
    const short8 z8 = (short8){0, 0, 0, 0, 0, 0, 0, 0};
#pragma unroll
    for (int ks = 0; ks < 2; ++ks) {
        short8 af = vr ? *(const short8*)&hactb[(size_t)gr * HOUT + ks * 32 + lg * 8] : z8;
#pragma unroll
        for (int ct = 0; ct < 3; ++ct) {
            short8 bf = *(const short8*)&W2t[(ct * 16 + lr) * HOUT + ks * 32 + lg * 8];
            acc[ct] = __builtin_amdgcn_mfma_f32_16x16x32_bf16(af, bf, acc[ct], 0, 0, 0);
        }
    }
    float av4[4], dv4[4];
#pragma unroll
    for (int q = 0; q < 4; ++q) {
        int r = row0 + lg * 4 + q;
        bool vw = r < n;
        float av = 0.f, dv = 0.f;
#pragma unroll
        for (int ct = 0; ct < 3; ++ct) {
            int c = ct * 16 + lr;
            if (c < NCLS) {
                float o = acc[ct][q];
                av += o * asw[c];
                dv += o * adw[c];
                if (vw) h2b[(size_t)r * NCLS + c] = f2b(o);
            }
        }
        av += __shfl_xor(av, 1); av += __shfl_xor(av, 2); av += __shfl_xor(av, 4); av += __shfl_xor(av, 8);
        dv += __shfl_xor(dv, 1); dv += __shfl_xor(dv, 2); dv += __shfl_xor(dv, 4); dv += __shfl_xor(dv, 8);
        av4[q] = av; dv4[q] = dv;
    }
#pragma unroll
    for (int q = 0; q < 4; ++q) {
        int r = row0 + lg * 4 + q;
        if (lr == q && r < n) as2[r] = av4[q];
        if (lr == 8 + q && r < n) ad2[r] = dv4[q];
    }
}

// ---------------- layer-2 aggregation + log_softmax: 2 nodes/wave, batch-4 ----------------

__global__ __launch_bounds__(256) void l2agg_k(const ushort* __restrict__ h2b, const float* __restrict__ as2,
                                               const float* __restrict__ ad2, const float* __restrict__ b2,
                                               const int2* __restrict__ rowse, const int* __restrict__ col,
                                               float* __restrict__ out, int n) {
    __shared__ int2 pk_all[4][2 * 40];
    int wid = threadIdx.x >> 6, lane = threadIdx.x & 63;
    int nA = (blockIdx.x * 4 + wid) * 2;
    if (nA >= n) return;
    int nB = nA + 1;
    int na = lane >> 5, sl = lane & 31;
    int node = nA + na;
    bool nodev = node < n;
    int4 rr = *(const int4*)&rowse[nA];
    if (nB >= n) { rr.z = rr.y; rr.w = rr.y; }
    int degA = rr.y - rr.x, degB = rr.w - rr.z;
    int st  = na ? rr.z : rr.x;
    int deg = na ? degB : degA;

    if (degA <= 32 && degB <= 32) {
        int2* pk = pk_all[wid];
        bool v = nodev && (sl < deg);
        int s = 0; float av = 0.f;
        if (v) { s = col[st + sl]; av = as2[s]; }
        float ad = nodev ? ad2[node] : 0.f;
        float ev = av + ad;
        float ee = v ? (ev >= 0.f ? ev : NEG * ev) : -1e30f;
        float m = ee;
        m = fmaxf(m, __shfl_xor(m, 1)); m = fmaxf(m, __shfl_xor(m, 2));
        m = fmaxf(m, __shfl_xor(m, 4)); m = fmaxf(m, __shfl_xor(m, 8));
        m = fmaxf(m, __shfl_xor(m, 16));
        float p = __expf(ee - m);
        float d = p;
        d += __shfl_xor(d, 1); d += __shfl_xor(d, 2); d += __shfl_xor(d, 4);
        d += __shfl_xor(d, 8); d += __shfl_xor(d, 16);
        float w = p / (d + 1e-16f);
        pk[na * 40 + sl] = make_int2(__float_as_int(w), s);
        __asm__ volatile("s_waitcnt lgkmcnt(0)" ::: "memory");
        __builtin_amdgcn_sched_barrier(0);
        // edge-pair gather, batch-4
        bool gact = sl < 20;
        int cl = sl % 10;
        int eo2 = gact ? (sl / 10) : 0;
        int jb = na * 40 + eo2;
        float acc0 = 0.f, acc1 = 0.f, acc2 = 0.f, acc3 = 0.f;
        int mdeg = max(degA, degB);
        for (int g0 = 0; 2 * g0 < mdeg; g0 += 4) {
            int2 qa = pk[jb + 2 * g0];
            int2 qb = pk[jb + 2 * g0 + 2];
            int2 qc = pk[jb + 2 * g0 + 4];
            int2 qd = pk[jb + 2 * g0 + 6];        // max slot 31 < 40; out-of-deg slots carry w=0
            if (gact) {
                uint2 ha = *(const uint2*)&h2b[(size_t)qa.y * NCLS + 4 * cl];
                uint2 hb = *(const uint2*)&h2b[(size_t)qb.y * NCLS + 4 * cl];
                uint2 hc = *(const uint2*)&h2b[(size_t)qc.y * NCLS + 4 * cl];
                uint2 hd = *(const uint2*)&h2b[(size_t)qd.y * NCLS + 4 * cl];
                float wa = __int_as_float(qa.x), wb = __int_as_float(qb.x);
                float wc = __int_as_float(qc.x), wd = __int_as_float(qd.x);
                acc0 += wa * b2f_lo(ha.x) + wb * b2f_lo(hb.x) + wc * b2f_lo(hc.x) + wd * b2f_lo(hd.x);
                acc1 += wa * b2f_hi(ha.x) + wb * b2f_hi(hb.x) + wc * b2f_hi(hc.x) + wd * b2f_hi(hd.x);
                acc2 += wa * b2f_lo(ha.y) + wb * b2f_lo(hb.y) + wc * b2f_lo(hc.y) + wd * b2f_lo(hd.y);
                acc3 += wa * b2f_hi(ha.y) + wb * b2f_hi(hb.y) + wc * b2f_hi(hc.y) + wd * b2f_hi(hd.y);
            }
        }
        // combine even/odd partials: lane sl<10 += lane sl+10
        int self = threadIdx.x & 63;
        float p0 = __shfl(acc0, self + 10);
        float p1 = __shfl(acc1, self + 10);
        float p2s = __shfl(acc2, self + 10);
        float p3 = __shfl(acc3, self + 10);
        bool fin = sl < 10;
        float z0, z1, z2, z3;
        if (fin) {
            float4 bb = *(const float4*)&b2[4 * cl];
            z0 = acc0 + p0 + bb.x; z1 = acc1 + p1 + bb.y;
            z2 = acc2 + p2s + bb.z; z3 = acc3 + p3 + bb.w;
        } else { z0 = z1 = z2 = z3 = -1e30f; }
        float zm = fin ? fmaxf(fmaxf(z0, z1), fmaxf(z2, z3)) : -1e30f;
        zm = fmaxf(zm, __shfl_xor(zm, 1)); zm = fmaxf(zm, __shfl_xor(zm, 2));
        zm = fmaxf(zm, __shfl_xor(zm, 4)); zm = fmaxf(zm, __shfl_xor(zm, 8));
        float ex = fin ? (__expf(z0 - zm) + __expf(z1 - zm) + __expf(z2 - zm) + __expf(z3 - zm)) : 0.f;
        ex += __shfl_xor(ex, 1); ex += __shfl_xor(ex, 2);
        ex += __shfl_xor(ex, 4); ex += __shfl_xor(ex, 8);
        float ls = logf(ex);
        if (fin && nodev) {
            float4 o = make_float4(z0 - zm - ls, z1 - zm - ls, z2 - zm - ls, z3 - zm - ls);
            *(float4*)&out[(size_t)node * NCLS + 4 * cl] = o;
        }
    } else {
        // rare fallback: serial online softmax per half, 20 lanes x 2ch (own tail)
        bool act = sl < 20;
        float z0, z1;
        float ad = nodev ? ad2[node] : 0.f;
        float m = -1e30f, den = 0.f, a0 = 0.f, a1 = 0.f;
        int en = st + deg;
        for (int e = st; e < en; ++e) {
            int s = col[e];
            float ev = as2[s] + ad;
            float ee = ev >= 0.f ? ev : NEG * ev;
            float mn = fmaxf(m, ee);
            float sc = __expf(m - mn), p = __expf(ee - mn);
            den = den * sc + p;
            if (act) {
                unsigned hv = *(const unsigned*)&h2b[(size_t)s * NCLS + 2 * sl];
                a0 = a0 * sc + p * b2f_lo(hv);
                a1 = a1 * sc + p * b2f_hi(hv);
            }
            m = mn;
        }
        if (act) {
            float2 bb = *(const float2*)&b2[2 * sl];
            z0 = a0 / (den + 1e-16f) + bb.x;
            z1 = a1 / (den + 1e-16f) + bb.y;
        } else { z0 = z1 = -1e30f; }
        float zm = fmaxf(z0, z1);
        zm = fmaxf(zm, __shfl_xor(zm, 1)); zm = fmaxf(zm, __shfl_xor(zm, 2));
        zm = fmaxf(zm, __shfl_xor(zm, 4)); zm = fmaxf(zm, __shfl_xor(zm, 8));
        zm = fmaxf(zm, __shfl_xor(zm, 16));
        float ex = act ? (__expf(z0 - zm) + __expf(z1 - zm)) : 0.f;
        ex += __shfl_xor(ex, 1); ex += __shfl_xor(ex, 2); ex += __shfl_xor(ex, 4);
        ex += __shfl_xor(ex, 8); ex += __shfl_xor(ex, 16);
        float ls = logf(ex);
        if (act && nodev) {
            float2 o = make_float2(z0 - zm - ls, z1 - zm - ls);
            *(float2*)&out[(size_t)node * NCLS + 2 * sl] = o;
        }
    }
}

// ---------------- host ----------------

extern "C" void kernel_launch(void* const* d_in, const int* in_sizes, int n_in,
                              void* d_out, int out_size, void* d_ws, size_t ws_size,
                              hipStream_t stream) {
    const float* x    = (const float*)d_in[0];
    const int*   ei   = (const int*)d_in[1];
    const float* W1   = (const float*)d_in[2];
    const float* asw1 = (const float*)d_in[3];
    const float* adw1 = (const float*)d_in[4];
    const float* b1   = (const float*)d_in[5];
    const float* W2   = (const float*)d_in[6];
    const float* asw2 = (const float*)d_in[7];
    const float* adw2 = (const float*)d_in[8];
    const float* b2   = (const float*)d_in[9];
    float* out = (float*)d_out;

    const int n = in_sizes[0] / F_IN;          // 100000
    const int E = in_sizes[1] / 2;             // 1600000
    const int Etot = E + n;
    const int nbuck = (n + DPB - 1) / DPB;     // 391
    const int npair = (n + 1) / 2;

    char* ws = (char*)d_ws;
    size_t off = 0;
    auto alloc = [&](size_t bytes) -> void* {
        void* p = ws + off;
        off = (off + bytes + 255) & ~(size_t)255;
        return p;
    };
    int*    gcur   = (int*)alloc((size_t)nbuck * 4);
    int2*   rowse  = (int2*)alloc((size_t)(n + 2) * 8);
    int*    col    = (int*)alloc((size_t)nbuck * CAP * 4);           // 12.6 MB (per-bucket padded)
    int*    bkt    = (int*)alloc((size_t)nbuck * CAP * 4);           // 12.6 MB (packed 4B)
    ushort* h1b    = (ushort*)alloc((size_t)n * HOUT * 2);           // 12.8 MB (reused as h2b)
    float*  as1    = (float*)alloc((size_t)n * HEADS * 4);
    float*  ad1    = (float*)alloc((size_t)n * HEADS * 4);
    ushort* hactb  = (ushort*)alloc((size_t)n * HOUT * 2);           // 12.8 MB
    ushort* Wtg    = (ushort*)alloc((size_t)HOUT * WLD * 2);
    ushort* W2t    = (ushort*)alloc((size_t)48 * HOUT * 2);
    ushort* h2b = h1b;   // h1b dead after l1agg
    float*  as2 = (float*)(h1b + (size_t)n * NCLS);
    float*  ad2 = as2 + n;

    const int g1 = (n + 127) / 128;                       // gemm1 blocks
    const int gpa = (Etot + 256 * EPT - 1) / (256 * EPT); // passA blocks
    const int gpb = nbuck;                                // passB blocks
    const int gat = (n * HEADS + 255) / 256;              // att1 blocks

    prep_k<<<142, 256, 0, stream>>>(W1, W2, gcur, Wtg, W2t, nbuck);
    work1_k<<<g1 + gpa, 256, 0, stream>>>(x, Wtg, h1b, n, ei, gcur, bkt, E, Etot, nbuck, g1);
    work2_k<<<gpb + gat, 256, 0, stream>>>(bkt, gcur, rowse, col, n,
                                           h1b, asw1, adw1, as1, ad1, gpb);
    l1agg_k<<<(npair + 3) / 4, 256, 0, stream>>>(h1b, as1, ad1, b1, rowse, col, hactb, n);
    g2_k<<<(n + 63) / 64, 256, 0, stream>>>(hactb, W2t, asw2, adw2, h2b, as2, ad2, n);
    l2agg_k<<<(npair + 3) / 4, 256, 0, stream>>>(h2b, as2, ad2, b2, rowse, col, out, n);
}